// Round 1
// baseline (722.849 us; speedup 1.0000x reference)
//
#include <hip/hip_runtime.h>

// ---------------------------------------------------------------------------
// GAT 2-layer forward. N=50000 nodes, E=800000 edges, C=256 channels/layer.
// Strategy: CSR (dst->edges) built once; per-node wave-parallel softmax+agg
// (no float atomics). fp32 everywhere for the correctness baseline.
// ---------------------------------------------------------------------------

__global__ __launch_bounds__(256) void gemm_f32(
    const float* __restrict__ A, const float* __restrict__ B,
    float* __restrict__ C, int M, int N, int K)
{
    // 64x64 tile, BK=16, 256 threads, 4x4 per thread.
    __shared__ __align__(16) float As[16][64];
    __shared__ __align__(16) float Bs[16][64];
    const int tid = threadIdx.x;
    const int tx = tid & 15, ty = tid >> 4;
    const int rowBase = blockIdx.y * 64, colBase = blockIdx.x * 64;
    const int arow = tid >> 2;          // 0..63
    const int akq  = (tid & 3) << 2;    // 0,4,8,12
    const int brow = tid >> 4;          // 0..15
    const int bcol = (tid & 15) << 2;   // 0..60
    float acc[4][4] = {};
    for (int k0 = 0; k0 < K; k0 += 16) {
        float4 av = make_float4(0.f, 0.f, 0.f, 0.f);
        int ar = rowBase + arow;
        if (ar < M) av = *(const float4*)(A + (size_t)ar * K + k0 + akq);
        As[akq + 0][arow] = av.x;
        As[akq + 1][arow] = av.y;
        As[akq + 2][arow] = av.z;
        As[akq + 3][arow] = av.w;
        *(float4*)&Bs[brow][bcol] =
            *(const float4*)(B + (size_t)(k0 + brow) * N + colBase + bcol);
        __syncthreads();
        #pragma unroll
        for (int kk = 0; kk < 16; ++kk) {
            float4 a4 = *(const float4*)&As[kk][ty << 2];
            float4 b4 = *(const float4*)&Bs[kk][tx << 2];
            float aa[4] = {a4.x, a4.y, a4.z, a4.w};
            float bb[4] = {b4.x, b4.y, b4.z, b4.w};
            #pragma unroll
            for (int i = 0; i < 4; ++i)
                #pragma unroll
                for (int j = 0; j < 4; ++j)
                    acc[i][j] = fmaf(aa[i], bb[j], acc[i][j]);
        }
        __syncthreads();
    }
    #pragma unroll
    for (int i = 0; i < 4; ++i) {
        int r = rowBase + (ty << 2) + i;
        if (r < M) {
            float4 o = make_float4(acc[i][0], acc[i][1], acc[i][2], acc[i][3]);
            *(float4*)(C + (size_t)r * N + colBase + (tx << 2)) = o;
        }
    }
}

// el[n,h] = dot(h[n,h,:], al[h,:]); er likewise. One wave per node, C=256.
__global__ __launch_bounds__(256) void eler_kernel(
    const float* __restrict__ h, const float* __restrict__ al,
    const float* __restrict__ ar, float* __restrict__ el,
    float* __restrict__ er, int n_nodes, int H)
{
    int wid = blockIdx.x * 4 + (threadIdx.x >> 6);
    if (wid >= n_nodes) return;
    int lane = threadIdx.x & 63;
    const float* hr = h + (size_t)wid * 256;
    float v0 = hr[lane], v1 = hr[64 + lane], v2 = hr[128 + lane], v3 = hr[192 + lane];
    // al/ar flat over 256 cols (col = head*Dhead + d in both H=1,2 cases)
    float p0 = v0 * al[lane] + v1 * al[64 + lane];
    float p1 = v2 * al[128 + lane] + v3 * al[192 + lane];
    float q0 = v0 * ar[lane] + v1 * ar[64 + lane];
    float q1 = v2 * ar[128 + lane] + v3 * ar[192 + lane];
    #pragma unroll
    for (int off = 32; off; off >>= 1) {
        p0 += __shfl_xor(p0, off); p1 += __shfl_xor(p1, off);
        q0 += __shfl_xor(q0, off); q1 += __shfl_xor(q1, off);
    }
    if (lane == 0) {
        if (H == 2) {
            el[wid * 2] = p0; el[wid * 2 + 1] = p1;
            er[wid * 2] = q0; er[wid * 2 + 1] = q1;
        } else {
            el[wid] = p0 + p1;
            er[wid] = q0 + q1;
        }
    }
}

__global__ void count_kernel(const int* __restrict__ dst, int* __restrict__ cnt, int E)
{
    int t = blockIdx.x * blockDim.x + threadIdx.x;
    if (t < E) atomicAdd(&cnt[dst[t]], 1);
}

__global__ __launch_bounds__(1024) void scan_kernel(
    const int* __restrict__ cnt, int* __restrict__ row,
    int* __restrict__ cursor, int n)
{
    __shared__ int sm[1024];
    __shared__ int carry;
    int t = threadIdx.x;
    if (t == 0) carry = 0;
    __syncthreads();
    for (int base = 0; base < n; base += 1024) {
        int v = (base + t < n) ? cnt[base + t] : 0;
        sm[t] = v;
        __syncthreads();
        for (int off = 1; off < 1024; off <<= 1) {
            int x = (t >= off) ? sm[t - off] : 0;
            __syncthreads();
            sm[t] += x;
            __syncthreads();
        }
        int excl = carry + sm[t] - v;
        if (base + t < n) { row[base + t] = excl; cursor[base + t] = excl; }
        int tot = sm[1023];
        __syncthreads();
        if (t == 0) carry += tot;
        __syncthreads();
    }
    if (t == 0) row[n] = carry;
}

__global__ void fill_kernel(const int* __restrict__ dst, int* __restrict__ cursor,
                            int* __restrict__ eid, int E)
{
    int t = blockIdx.x * blockDim.x + threadIdx.x;
    if (t < E) {
        int pos = atomicAdd(&cursor[dst[t]], 1);
        eid[pos] = t;
    }
}

__global__ void edge_kernel(const float* __restrict__ el, const float* __restrict__ er,
                            const int* __restrict__ src, const int* __restrict__ dst,
                            float* __restrict__ e, int E, int H)
{
    int t = blockIdx.x * blockDim.x + threadIdx.x;
    if (t >= E) return;
    int s = src[t], d = dst[t];
    for (int h = 0; h < H; ++h) {
        float v = el[s * H + h] + er[d * H + h];
        e[t * H + h] = (v > 0.f) ? v : 0.2f * v;
    }
}

// One wave per dst node: segment softmax + weighted gather-sum of h[src].
__global__ __launch_bounds__(256) void agg_kernel(
    const float* __restrict__ h, const float* __restrict__ e,
    const int* __restrict__ row, const int* __restrict__ eidx,
    const int* __restrict__ src, const float* __restrict__ bias,
    float* __restrict__ out, int n_nodes, int H, int do_relu, int zero0)
{
    int wid = blockIdx.x * 4 + (threadIdx.x >> 6);
    if (wid >= n_nodes) return;
    int lane = threadIdx.x & 63;
    int beg = row[wid], end = row[wid + 1];

    float m0 = -1e30f, m1 = -1e30f;
    for (int i = beg + lane; i < end; i += 64) {
        int ei = eidx[i];
        m0 = fmaxf(m0, e[ei * H]);
        if (H == 2) m1 = fmaxf(m1, e[ei * 2 + 1]);
    }
    #pragma unroll
    for (int off = 32; off; off >>= 1) {
        m0 = fmaxf(m0, __shfl_xor(m0, off));
        m1 = fmaxf(m1, __shfl_xor(m1, off));
    }
    float s0 = 0.f, s1 = 0.f;
    for (int i = beg + lane; i < end; i += 64) {
        int ei = eidx[i];
        s0 += __expf(e[ei * H] - m0);
        if (H == 2) s1 += __expf(e[ei * 2 + 1] - m1);
    }
    #pragma unroll
    for (int off = 32; off; off >>= 1) {
        s0 += __shfl_xor(s0, off);
        s1 += __shfl_xor(s1, off);
    }
    float r0 = (s0 > 0.f) ? 1.f / s0 : 0.f;
    float r1 = (s1 > 0.f) ? 1.f / s1 : 0.f;

    float a0 = 0.f, a1 = 0.f, a2 = 0.f, a3 = 0.f;
    for (int i = beg; i < end; ++i) {
        int ei = eidx[i];
        int sn = src[ei];
        float w0 = __expf(e[ei * H] - m0) * r0;
        float w1 = (H == 2) ? __expf(e[ei * 2 + 1] - m1) * r1 : w0;
        const float* hr = h + (size_t)sn * 256;
        a0 = fmaf(w0, hr[lane],        a0);
        a1 = fmaf(w0, hr[64 + lane],   a1);
        a2 = fmaf(w1, hr[128 + lane],  a2);
        a3 = fmaf(w1, hr[192 + lane],  a3);
    }
    float o0 = a0 + bias[lane];
    float o1 = a1 + bias[64 + lane];
    float o2 = a2 + bias[128 + lane];
    float o3 = a3 + bias[192 + lane];
    if (do_relu) {
        o0 = fmaxf(o0, 0.f); o1 = fmaxf(o1, 0.f);
        o2 = fmaxf(o2, 0.f); o3 = fmaxf(o3, 0.f);
    }
    if (zero0 && wid == 0) { o0 = o1 = o2 = o3 = 0.f; }
    size_t base = (size_t)wid * 256;
    out[base + lane]        = o0;
    out[base + 64 + lane]   = o1;
    out[base + 128 + lane]  = o2;
    out[base + 192 + lane]  = o3;
}

extern "C" void kernel_launch(void* const* d_in, const int* in_sizes, int n_in,
                              void* d_out, int out_size, void* d_ws, size_t ws_size,
                              hipStream_t stream)
{
    const float* emb = (const float*)d_in[0];
    const float* W0  = (const float*)d_in[1];
    const float* al0 = (const float*)d_in[2];
    const float* ar0 = (const float*)d_in[3];
    const float* b0  = (const float*)d_in[4];
    const float* W1  = (const float*)d_in[5];
    const float* al1 = (const float*)d_in[6];
    const float* ar1 = (const float*)d_in[7];
    const float* b1  = (const float*)d_in[8];
    const int* src   = (const int*)d_in[9];
    const int* dst   = (const int*)d_in[10];
    const int N = in_sizes[0] / 128;     // 50000
    const int E = in_sizes[9];           // 800000
    float* outp = (float*)d_out;

    char* w = (char*)d_ws;
    auto alloc = [&](size_t bytes) {
        char* p = w;
        w += (bytes + 255) & ~(size_t)255;
        return p;
    };
    float* hbuf  = (float*)alloc((size_t)N * 256 * 4);  // h0, then h1
    float* el    = (float*)alloc((size_t)N * 2 * 4);
    float* er    = (float*)alloc((size_t)N * 2 * 4);
    float* ebuf  = (float*)alloc((size_t)E * 2 * 4);
    int* cnt     = (int*)alloc((size_t)N * 4);
    int* rowp    = (int*)alloc((size_t)(N + 1) * 4);
    int* cursor  = (int*)alloc((size_t)N * 4);
    int* eid     = (int*)alloc((size_t)E * 4);

    // --- CSR build (dst -> edge list), shared by both layers ---
    hipMemsetAsync(cnt, 0, (size_t)N * 4, stream);
    count_kernel<<<(E + 255) / 256, 256, 0, stream>>>(dst, cnt, E);
    scan_kernel<<<1, 1024, 0, stream>>>(cnt, rowp, cursor, N);
    fill_kernel<<<(E + 255) / 256, 256, 0, stream>>>(dst, cursor, eid, E);

    // --- layer 0 (H=2, Dout=128): x1 = relu(agg + b0), stored in d_out ---
    gemm_f32<<<dim3(4, (N + 63) / 64), 256, 0, stream>>>(emb, W0, hbuf, N, 256, 128);
    eler_kernel<<<(N + 3) / 4, 256, 0, stream>>>(hbuf, al0, ar0, el, er, N, 2);
    edge_kernel<<<(E + 255) / 256, 256, 0, stream>>>(el, er, src, dst, ebuf, E, 2);
    agg_kernel<<<(N + 3) / 4, 256, 0, stream>>>(hbuf, ebuf, rowp, eid, src, b0,
                                                outp, N, 2, /*relu=*/1, /*zero0=*/0);

    // --- layer 1 (H=1, Dout=256): out = agg + b1, row0 zeroed ---
    gemm_f32<<<dim3(4, (N + 63) / 64), 256, 0, stream>>>(outp, W1, hbuf, N, 256, 256);
    eler_kernel<<<(N + 3) / 4, 256, 0, stream>>>(hbuf, al1, ar1, el, er, N, 1);
    edge_kernel<<<(E + 255) / 256, 256, 0, stream>>>(el, er, src, dst, ebuf, E, 1);
    agg_kernel<<<(N + 3) / 4, 256, 0, stream>>>(hbuf, ebuf, rowp, eid, src, b1,
                                                outp, N, 1, /*relu=*/0, /*zero0=*/1);
}

// Round 3
// 499.097 us; speedup vs baseline: 1.4483x; 1.4483x over previous
//
#include <hip/hip_runtime.h>

// ---------------------------------------------------------------------------
// GAT 2-layer forward, round 3 (= round 2 + H=2 softmax-stats fix).
//  - h stored bf16 (halves the dominant gather traffic in agg)
//  - GEMMs via mfma_f32_16x16x32_bf16 (128x64 tile, BK=64, XOR-swizzled LDS)
//  - agg H=2: each 32-lane half walks ALL edges (stride 32), reduce within half
// ---------------------------------------------------------------------------

typedef __attribute__((ext_vector_type(8))) short short8v;   // 8 bf16
typedef __attribute__((ext_vector_type(4))) float f32x4;

__device__ inline unsigned short f2bf(float x) {
    union { float f; unsigned int u; } v; v.f = x;
    unsigned int r = v.u + 0x7fffu + ((v.u >> 16) & 1u);   // RNE
    return (unsigned short)(r >> 16);
}
__device__ inline float bf2f(unsigned short h) {
    union { unsigned int u; float f; } v; v.u = ((unsigned int)h) << 16;
    return v.f;
}

// ---------------- converts ----------------
__global__ void conv_f32_bf16(const float* __restrict__ in,
                              unsigned short* __restrict__ out, int n)
{
    int t = (blockIdx.x * blockDim.x + threadIdx.x) * 4;
    if (t + 3 < n) {
        float4 v = *(const float4*)(in + t);
        ushort4 o;
        o.x = f2bf(v.x); o.y = f2bf(v.y); o.z = f2bf(v.z); o.w = f2bf(v.w);
        *(ushort4*)(out + t) = o;
    } else {
        for (int i = t; i < n; ++i) out[i] = f2bf(in[i]);
    }
}

// W [K][N] fp32 -> Wt [N][K] bf16
__global__ void convW(const float* __restrict__ W, unsigned short* __restrict__ Wt,
                      int K, int N)
{
    int t = blockIdx.x * blockDim.x + threadIdx.x;
    if (t < K * N) {
        int k = t / N, n2 = t - k * N;
        Wt[n2 * K + k] = f2bf(W[t]);
    }
}

// ---------------- bf16 MFMA GEMM: C[M][N] = A[M][K] @ Bt[N][K]^T ----------------
// block tile 128x64, BK=64, 256 threads (4 waves), wave computes 32x64.
__global__ __launch_bounds__(256) void gemm_bf16(
    const unsigned short* __restrict__ A, const unsigned short* __restrict__ Bt,
    unsigned short* __restrict__ C, int M, int N, int K)
{
    __shared__ __align__(16) unsigned short As[128 * 64];
    __shared__ __align__(16) unsigned short Bs[64 * 64];
    const int tid = threadIdx.x;
    const int lane = tid & 63, wv = tid >> 6;
    const int rowBase = blockIdx.x * 128;
    const int colBase = blockIdx.y * 64;

    f32x4 acc[2][4];
    #pragma unroll
    for (int i = 0; i < 2; ++i)
        #pragma unroll
        for (int j = 0; j < 4; ++j)
            acc[i][j] = (f32x4){0.f, 0.f, 0.f, 0.f};

    for (int k0 = 0; k0 < K; k0 += 64) {
        // stage A: 128 rows x 8 chunks(16B); dest chunk = cc ^ (row&7)
        #pragma unroll
        for (int c = tid; c < 128 * 8; c += 256) {
            int row = c >> 3, cc = c & 7;
            int gr = rowBase + row; if (gr >= M) gr = M - 1;
            int4 v = *(const int4*)(A + (size_t)gr * K + k0 + cc * 8);
            *(int4*)&As[row * 64 + (cc ^ (row & 7)) * 8] = v;
        }
        // stage B: 64 rows(N) x 8 chunks
        #pragma unroll
        for (int c = tid; c < 64 * 8; c += 256) {
            int n2 = c >> 3, cc = c & 7;
            int4 v = *(const int4*)(Bt + (size_t)(colBase + n2) * K + k0 + cc * 8);
            *(int4*)&Bs[n2 * 64 + (cc ^ (n2 & 7)) * 8] = v;
        }
        __syncthreads();

        #pragma unroll
        for (int ks = 0; ks < 64; ks += 32) {
            int kchunk = (ks >> 3) + (lane >> 4);   // 0..7
            short8v af[2], bfr[4];
            #pragma unroll
            for (int fm = 0; fm < 2; ++fm) {
                int ml = wv * 32 + fm * 16 + (lane & 15);
                af[fm] = *(const short8v*)&As[ml * 64 + (kchunk ^ (ml & 7)) * 8];
            }
            #pragma unroll
            for (int fi = 0; fi < 4; ++fi) {
                int nl = fi * 16 + (lane & 15);
                bfr[fi] = *(const short8v*)&Bs[nl * 64 + (kchunk ^ (nl & 7)) * 8];
            }
            #pragma unroll
            for (int fm = 0; fm < 2; ++fm)
                #pragma unroll
                for (int fi = 0; fi < 4; ++fi)
                    acc[fm][fi] = __builtin_amdgcn_mfma_f32_16x16x32_bf16(
                        af[fm], bfr[fi], acc[fm][fi], 0, 0, 0);
        }
        __syncthreads();
    }

    // epilogue: D row = (lane>>4)*4 + r, col = lane&15
    #pragma unroll
    for (int fm = 0; fm < 2; ++fm) {
        #pragma unroll
        for (int r = 0; r < 4; ++r) {
            int row = rowBase + wv * 32 + fm * 16 + (lane >> 4) * 4 + r;
            if (row < M) {
                #pragma unroll
                for (int fi = 0; fi < 4; ++fi) {
                    int col = colBase + fi * 16 + (lane & 15);
                    C[(size_t)row * N + col] = f2bf(acc[fm][fi][r]);
                }
            }
        }
    }
}

// ---------------- el/er: dot(h_row, al/ar) ----------------
__global__ __launch_bounds__(256) void eler_kernel(
    const unsigned short* __restrict__ h, const float* __restrict__ al,
    const float* __restrict__ ar, float* __restrict__ el,
    float* __restrict__ er, int n_nodes, int H)
{
    int wid = blockIdx.x * 4 + (threadIdx.x >> 6);
    if (wid >= n_nodes) return;
    int lane = threadIdx.x & 63;
    ushort4 hv = *(const ushort4*)(h + (size_t)wid * 256 + lane * 4);
    float4 a4 = *(const float4*)(al + lane * 4);
    float4 r4 = *(const float4*)(ar + lane * 4);
    float h0 = bf2f(hv.x), h1 = bf2f(hv.y), h2 = bf2f(hv.z), h3 = bf2f(hv.w);
    float p = h0 * a4.x + h1 * a4.y + h2 * a4.z + h3 * a4.w;
    float q = h0 * r4.x + h1 * r4.y + h2 * r4.z + h3 * r4.w;
    int lim = (H == 2) ? 16 : 32;
    for (int off = lim; off; off >>= 1) {
        p += __shfl_xor(p, off);
        q += __shfl_xor(q, off);
    }
    if (H == 2) {
        if (lane == 0)  { el[wid * 2]     = p; er[wid * 2]     = q; }
        if (lane == 32) { el[wid * 2 + 1] = p; er[wid * 2 + 1] = q; }
    } else if (lane == 0) {
        el[wid] = p; er[wid] = q;
    }
}

// ---------------- CSR build ----------------
__global__ void count_kernel(const int* __restrict__ dst, int* __restrict__ cnt, int E)
{
    int t = blockIdx.x * blockDim.x + threadIdx.x;
    if (t < E) atomicAdd(&cnt[dst[t]], 1);
}

__global__ __launch_bounds__(1024) void scan_kernel(
    const int* __restrict__ cnt, int* __restrict__ row,
    int* __restrict__ cursor, int n)
{
    __shared__ int part[1024];
    int t = threadIdx.x;
    int ch = (n + 1023) >> 10;
    int b = t * ch, e = b + ch; if (e > n) e = n;
    int s = 0;
    for (int i = b; i < e; ++i) s += cnt[i];
    part[t] = s;
    __syncthreads();
    for (int off = 1; off < 1024; off <<= 1) {
        int x = (t >= off) ? part[t - off] : 0;
        __syncthreads();
        part[t] += x;
        __syncthreads();
    }
    int run = part[t] - s;
    for (int i = b; i < e; ++i) { row[i] = run; cursor[i] = run; run += cnt[i]; }
    if (t == 1023) row[n] = part[1023];
}

__global__ void fill_kernel(const int* __restrict__ dst, int* __restrict__ cursor,
                            int* __restrict__ eid, int E)
{
    int t = blockIdx.x * blockDim.x + threadIdx.x;
    if (t < E) {
        int pos = atomicAdd(&cursor[dst[t]], 1);
        eid[pos] = t;
    }
}

__global__ void edge_kernel(const float* __restrict__ el, const float* __restrict__ er,
                            const int* __restrict__ src, const int* __restrict__ dst,
                            float* __restrict__ e, int E, int H)
{
    int t = blockIdx.x * blockDim.x + threadIdx.x;
    if (t >= E) return;
    int s = src[t], d = dst[t];
    for (int h = 0; h < H; ++h) {
        float v = el[s * H + h] + er[d * H + h];
        e[t * H + h] = (v > 0.f) ? v : 0.2f * v;
    }
}

// ---------------- per-dst-node softmax + weighted gather (bf16 h) ----------------
// H=2: lanes 0..31 handle head 0 (channels 0..127), lanes 32..63 head 1;
//      each 32-lane half walks ALL edges (stride 32), reduces within the half.
// H=1: all 64 lanes walk edges stride 64, full-wave reduce.
__global__ __launch_bounds__(256) void agg_kernel(
    const unsigned short* __restrict__ h, const float* __restrict__ e,
    const int* __restrict__ row, const int* __restrict__ eidx,
    const int* __restrict__ src, const float* __restrict__ bias,
    float* __restrict__ outf, unsigned short* __restrict__ outb,
    int n_nodes, int H, int do_relu, int zero0)
{
    int wid = blockIdx.x * 4 + (threadIdx.x >> 6);
    if (wid >= n_nodes) return;
    int lane = threadIdx.x & 63;
    int beg = row[wid], end = row[wid + 1];
    int hsel = (H == 2 && lane >= 32) ? 1 : 0;
    int lim    = (H == 2) ? 16 : 32;
    int stride = (H == 2) ? 32 : 64;
    int l0     = (H == 2) ? (lane & 31) : lane;

    float m = -1e30f;
    for (int i = beg + l0; i < end; i += stride)
        m = fmaxf(m, e[eidx[i] * H + hsel]);
    for (int off = lim; off; off >>= 1) m = fmaxf(m, __shfl_xor(m, off));

    float s = 0.f;
    for (int i = beg + l0; i < end; i += stride)
        s += __expf(e[eidx[i] * H + hsel] - m);
    for (int off = lim; off; off >>= 1) s += __shfl_xor(s, off);
    float r = (s > 0.f) ? 1.f / s : 0.f;

    float aA0 = 0.f, aA1 = 0.f, aA2 = 0.f, aA3 = 0.f;
    float aB0 = 0.f, aB1 = 0.f, aB2 = 0.f, aB3 = 0.f;
    int i = beg;
    for (; i + 1 < end; i += 2) {
        int e0 = eidx[i], e1 = eidx[i + 1];
        int s0 = src[e0], s1 = src[e1];
        float w0 = __expf(e[e0 * H + hsel] - m) * r;
        float w1 = __expf(e[e1 * H + hsel] - m) * r;
        ushort4 h0 = *(const ushort4*)(h + (size_t)s0 * 256 + lane * 4);
        ushort4 h1 = *(const ushort4*)(h + (size_t)s1 * 256 + lane * 4);
        aA0 = fmaf(w0, bf2f(h0.x), aA0); aB0 = fmaf(w1, bf2f(h1.x), aB0);
        aA1 = fmaf(w0, bf2f(h0.y), aA1); aB1 = fmaf(w1, bf2f(h1.y), aB1);
        aA2 = fmaf(w0, bf2f(h0.z), aA2); aB2 = fmaf(w1, bf2f(h1.z), aB2);
        aA3 = fmaf(w0, bf2f(h0.w), aA3); aB3 = fmaf(w1, bf2f(h1.w), aB3);
    }
    if (i < end) {
        int e0 = eidx[i];
        int s0 = src[e0];
        float w0 = __expf(e[e0 * H + hsel] - m) * r;
        ushort4 h0 = *(const ushort4*)(h + (size_t)s0 * 256 + lane * 4);
        aA0 = fmaf(w0, bf2f(h0.x), aA0);
        aA1 = fmaf(w0, bf2f(h0.y), aA1);
        aA2 = fmaf(w0, bf2f(h0.z), aA2);
        aA3 = fmaf(w0, bf2f(h0.w), aA3);
    }

    float4 b4 = *(const float4*)(bias + lane * 4);
    float o0 = aA0 + aB0 + b4.x;
    float o1 = aA1 + aB1 + b4.y;
    float o2 = aA2 + aB2 + b4.z;
    float o3 = aA3 + aB3 + b4.w;
    if (do_relu) {
        o0 = fmaxf(o0, 0.f); o1 = fmaxf(o1, 0.f);
        o2 = fmaxf(o2, 0.f); o3 = fmaxf(o3, 0.f);
    }
    if (zero0 && wid == 0) { o0 = o1 = o2 = o3 = 0.f; }
    size_t base = (size_t)wid * 256 + lane * 4;
    if (outb) {
        ushort4 o; o.x = f2bf(o0); o.y = f2bf(o1); o.z = f2bf(o2); o.w = f2bf(o3);
        *(ushort4*)(outb + base) = o;
    } else {
        *(float4*)(outf + base) = make_float4(o0, o1, o2, o3);
    }
}

extern "C" void kernel_launch(void* const* d_in, const int* in_sizes, int n_in,
                              void* d_out, int out_size, void* d_ws, size_t ws_size,
                              hipStream_t stream)
{
    const float* emb = (const float*)d_in[0];
    const float* W0  = (const float*)d_in[1];
    const float* al0 = (const float*)d_in[2];
    const float* ar0 = (const float*)d_in[3];
    const float* b0  = (const float*)d_in[4];
    const float* W1  = (const float*)d_in[5];
    const float* al1 = (const float*)d_in[6];
    const float* ar1 = (const float*)d_in[7];
    const float* b1  = (const float*)d_in[8];
    const int* src   = (const int*)d_in[9];
    const int* dst   = (const int*)d_in[10];
    const int N = in_sizes[0] / 128;     // 50000
    const int E = in_sizes[9];           // 800000
    float* outp = (float*)d_out;

    char* w = (char*)d_ws;
    auto alloc = [&](size_t bytes) {
        char* p = w;
        w += (bytes + 255) & ~(size_t)255;
        return p;
    };
    unsigned short* hb  = (unsigned short*)alloc((size_t)N * 256 * 2); // h0/h1 bf16
    unsigned short* x1b = (unsigned short*)alloc((size_t)N * 256 * 2); // x1 bf16
    unsigned short* embb = x1b;  // alias: emb bf16 lives here until agg0 writes x1
    float* ebuf = (float*)alloc((size_t)E * 2 * 4);
    int* eid    = (int*)alloc((size_t)E * 4);
    int* rowp   = (int*)alloc((size_t)(N + 1) * 4);
    float* el   = (float*)alloc((size_t)N * 2 * 4);
    float* er   = (float*)alloc((size_t)N * 2 * 4);
    int* cnt    = (int*)el;     // alias: dead before eler writes el
    int* cursor = (int*)er;     // alias: dead before eler writes er
    unsigned short* W0t = (unsigned short*)alloc(256 * 128 * 2);
    unsigned short* W1t = (unsigned short*)alloc(256 * 256 * 2);

    // converts
    conv_f32_bf16<<<(N * 128 / 4 + 255) / 256, 256, 0, stream>>>(emb, embb, N * 128);
    convW<<<(128 * 256 + 255) / 256, 256, 0, stream>>>(W0, W0t, 128, 256);
    convW<<<(256 * 256 + 255) / 256, 256, 0, stream>>>(W1, W1t, 256, 256);

    // CSR build (dst -> edge list)
    hipMemsetAsync(cnt, 0, (size_t)N * 4, stream);
    count_kernel<<<(E + 255) / 256, 256, 0, stream>>>(dst, cnt, E);
    scan_kernel<<<1, 1024, 0, stream>>>(cnt, rowp, cursor, N);
    fill_kernel<<<(E + 255) / 256, 256, 0, stream>>>(dst, cursor, eid, E);

    // --- layer 0 (H=2): x1 = relu(agg + b0) -> bf16 x1b ---
    gemm_bf16<<<dim3((N + 127) / 128, 4), 256, 0, stream>>>(embb, W0t, hb, N, 256, 128);
    eler_kernel<<<(N + 3) / 4, 256, 0, stream>>>(hb, al0, ar0, el, er, N, 2);
    edge_kernel<<<(E + 255) / 256, 256, 0, stream>>>(el, er, src, dst, ebuf, E, 2);
    agg_kernel<<<(N + 3) / 4, 256, 0, stream>>>(hb, ebuf, rowp, eid, src, b0,
                                                nullptr, x1b, N, 2, 1, 0);

    // --- layer 1 (H=1): out = agg + b1, row0 zeroed, fp32 out ---
    gemm_bf16<<<dim3((N + 127) / 128, 4), 256, 0, stream>>>(x1b, W1t, hb, N, 256, 256);
    eler_kernel<<<(N + 3) / 4, 256, 0, stream>>>(hb, al1, ar1, el, er, N, 1);
    edge_kernel<<<(E + 255) / 256, 256, 0, stream>>>(el, er, src, dst, ebuf, E, 1);
    agg_kernel<<<(N + 3) / 4, 256, 0, stream>>>(hb, ebuf, rowp, eid, src, b1,
                                                outp, nullptr, N, 1, 0, 1);
}

// Round 4
// 382.813 us; speedup vs baseline: 1.8883x; 1.3038x over previous
//
#include <hip/hip_runtime.h>

// ---------------------------------------------------------------------------
// GAT 2-layer forward, round 4.
//  - parallel 3-phase CSR scan (replaces 109us single-block scan)
//  - agg weighted loop unrolled 4x (more gathers in flight)
//  - h stored bf16; GEMMs via mfma_f32_16x16x32_bf16
// ---------------------------------------------------------------------------

typedef __attribute__((ext_vector_type(8))) short short8v;   // 8 bf16
typedef __attribute__((ext_vector_type(4))) float f32x4;

__device__ inline unsigned short f2bf(float x) {
    union { float f; unsigned int u; } v; v.f = x;
    unsigned int r = v.u + 0x7fffu + ((v.u >> 16) & 1u);   // RNE
    return (unsigned short)(r >> 16);
}
__device__ inline float bf2f(unsigned short h) {
    union { unsigned int u; float f; } v; v.u = ((unsigned int)h) << 16;
    return v.f;
}

// ---------------- converts ----------------
__global__ void conv_f32_bf16(const float* __restrict__ in,
                              unsigned short* __restrict__ out, int n)
{
    int t = (blockIdx.x * blockDim.x + threadIdx.x) * 4;
    if (t + 3 < n) {
        float4 v = *(const float4*)(in + t);
        ushort4 o;
        o.x = f2bf(v.x); o.y = f2bf(v.y); o.z = f2bf(v.z); o.w = f2bf(v.w);
        *(ushort4*)(out + t) = o;
    } else {
        for (int i = t; i < n; ++i) out[i] = f2bf(in[i]);
    }
}

// W [K][N] fp32 -> Wt [N][K] bf16
__global__ void convW(const float* __restrict__ W, unsigned short* __restrict__ Wt,
                      int K, int N)
{
    int t = blockIdx.x * blockDim.x + threadIdx.x;
    if (t < K * N) {
        int k = t / N, n2 = t - k * N;
        Wt[n2 * K + k] = f2bf(W[t]);
    }
}

// ---------------- bf16 MFMA GEMM: C[M][N] = A[M][K] @ Bt[N][K]^T ----------------
__global__ __launch_bounds__(256) void gemm_bf16(
    const unsigned short* __restrict__ A, const unsigned short* __restrict__ Bt,
    unsigned short* __restrict__ C, int M, int N, int K)
{
    __shared__ __align__(16) unsigned short As[128 * 64];
    __shared__ __align__(16) unsigned short Bs[64 * 64];
    const int tid = threadIdx.x;
    const int lane = tid & 63, wv = tid >> 6;
    const int rowBase = blockIdx.x * 128;
    const int colBase = blockIdx.y * 64;

    f32x4 acc[2][4];
    #pragma unroll
    for (int i = 0; i < 2; ++i)
        #pragma unroll
        for (int j = 0; j < 4; ++j)
            acc[i][j] = (f32x4){0.f, 0.f, 0.f, 0.f};

    for (int k0 = 0; k0 < K; k0 += 64) {
        #pragma unroll
        for (int c = tid; c < 128 * 8; c += 256) {
            int row = c >> 3, cc = c & 7;
            int gr = rowBase + row; if (gr >= M) gr = M - 1;
            int4 v = *(const int4*)(A + (size_t)gr * K + k0 + cc * 8);
            *(int4*)&As[row * 64 + (cc ^ (row & 7)) * 8] = v;
        }
        #pragma unroll
        for (int c = tid; c < 64 * 8; c += 256) {
            int n2 = c >> 3, cc = c & 7;
            int4 v = *(const int4*)(Bt + (size_t)(colBase + n2) * K + k0 + cc * 8);
            *(int4*)&Bs[n2 * 64 + (cc ^ (n2 & 7)) * 8] = v;
        }
        __syncthreads();

        #pragma unroll
        for (int ks = 0; ks < 64; ks += 32) {
            int kchunk = (ks >> 3) + (lane >> 4);   // 0..7
            short8v af[2], bfr[4];
            #pragma unroll
            for (int fm = 0; fm < 2; ++fm) {
                int ml = wv * 32 + fm * 16 + (lane & 15);
                af[fm] = *(const short8v*)&As[ml * 64 + (kchunk ^ (ml & 7)) * 8];
            }
            #pragma unroll
            for (int fi = 0; fi < 4; ++fi) {
                int nl = fi * 16 + (lane & 15);
                bfr[fi] = *(const short8v*)&Bs[nl * 64 + (kchunk ^ (nl & 7)) * 8];
            }
            #pragma unroll
            for (int fm = 0; fm < 2; ++fm)
                #pragma unroll
                for (int fi = 0; fi < 4; ++fi)
                    acc[fm][fi] = __builtin_amdgcn_mfma_f32_16x16x32_bf16(
                        af[fm], bfr[fi], acc[fm][fi], 0, 0, 0);
        }
        __syncthreads();
    }

    #pragma unroll
    for (int fm = 0; fm < 2; ++fm) {
        #pragma unroll
        for (int r = 0; r < 4; ++r) {
            int row = rowBase + wv * 32 + fm * 16 + (lane >> 4) * 4 + r;
            if (row < M) {
                #pragma unroll
                for (int fi = 0; fi < 4; ++fi) {
                    int col = colBase + fi * 16 + (lane & 15);
                    C[(size_t)row * N + col] = f2bf(acc[fm][fi][r]);
                }
            }
        }
    }
}

// ---------------- el/er ----------------
__global__ __launch_bounds__(256) void eler_kernel(
    const unsigned short* __restrict__ h, const float* __restrict__ al,
    const float* __restrict__ ar, float* __restrict__ el,
    float* __restrict__ er, int n_nodes, int H)
{
    int wid = blockIdx.x * 4 + (threadIdx.x >> 6);
    if (wid >= n_nodes) return;
    int lane = threadIdx.x & 63;
    ushort4 hv = *(const ushort4*)(h + (size_t)wid * 256 + lane * 4);
    float4 a4 = *(const float4*)(al + lane * 4);
    float4 r4 = *(const float4*)(ar + lane * 4);
    float h0 = bf2f(hv.x), h1 = bf2f(hv.y), h2 = bf2f(hv.z), h3 = bf2f(hv.w);
    float p = h0 * a4.x + h1 * a4.y + h2 * a4.z + h3 * a4.w;
    float q = h0 * r4.x + h1 * r4.y + h2 * r4.z + h3 * r4.w;
    int lim = (H == 2) ? 16 : 32;
    for (int off = lim; off; off >>= 1) {
        p += __shfl_xor(p, off);
        q += __shfl_xor(q, off);
    }
    if (H == 2) {
        if (lane == 0)  { el[wid * 2]     = p; er[wid * 2]     = q; }
        if (lane == 32) { el[wid * 2 + 1] = p; er[wid * 2 + 1] = q; }
    } else if (lane == 0) {
        el[wid] = p; er[wid] = q;
    }
}

// ---------------- CSR build ----------------
__global__ void count_kernel(const int* __restrict__ dst, int* __restrict__ cnt, int E)
{
    int t = blockIdx.x * blockDim.x + threadIdx.x;
    if (t < E) atomicAdd(&cnt[dst[t]], 1);
}

// Phase A: per-1024-chunk block sums
__global__ __launch_bounds__(256) void scan_partial(const int* __restrict__ cnt,
                                                    int* __restrict__ bsum, int n)
{
    int t = threadIdx.x;
    int idx = blockIdx.x * 1024 + t * 4;
    int4 v = make_int4(0, 0, 0, 0);
    if (idx + 3 < n) v = *(const int4*)(cnt + idx);
    else if (idx < n) {
        v.x = cnt[idx];
        if (idx + 1 < n) v.y = cnt[idx + 1];
        if (idx + 2 < n) v.z = cnt[idx + 2];
    }
    int s = v.x + v.y + v.z + v.w;
    #pragma unroll
    for (int off = 32; off; off >>= 1) s += __shfl_xor(s, off);
    __shared__ int ws[4];
    if ((t & 63) == 0) ws[t >> 6] = s;
    __syncthreads();
    if (t == 0) bsum[blockIdx.x] = ws[0] + ws[1] + ws[2] + ws[3];
}

// Phase B: exclusive scan of block sums (nb<=64 fast path); also row[n]=E.
__global__ void scan_bsum(int* __restrict__ bsum, int* __restrict__ row,
                          int nb, int n, int E)
{
    int t = threadIdx.x;   // 64 threads
    if (nb <= 64) {
        int v = (t < nb) ? bsum[t] : 0;
        int x = v;
        #pragma unroll
        for (int off = 1; off < 64; off <<= 1) {
            int y = __shfl_up(x, off);
            if (t >= off) x += y;
        }
        if (t < nb) bsum[t] = x - v;
    } else if (t == 0) {
        int run = 0;
        for (int i = 0; i < nb; ++i) { int v = bsum[i]; bsum[i] = run; run += v; }
    }
    if (t == 0) row[n] = E;
}

// Phase C: in-block exclusive scan + block offset -> row, cursor
__global__ __launch_bounds__(256) void scan_final(
    const int* __restrict__ cnt, const int* __restrict__ bsum,
    int* __restrict__ row, int* __restrict__ cursor, int n)
{
    int t = threadIdx.x;
    int lane = t & 63;
    int idx = blockIdx.x * 1024 + t * 4;
    int4 v = make_int4(0, 0, 0, 0);
    if (idx + 3 < n) v = *(const int4*)(cnt + idx);
    else if (idx < n) {
        v.x = cnt[idx];
        if (idx + 1 < n) v.y = cnt[idx + 1];
        if (idx + 2 < n) v.z = cnt[idx + 2];
    }
    int s1 = v.x + v.y, s2 = s1 + v.z, s3 = s2 + v.w;
    int tsum = s3;
    int x = tsum;
    #pragma unroll
    for (int off = 1; off < 64; off <<= 1) {
        int y = __shfl_up(x, off);
        if (lane >= off) x += y;
    }
    int wex = x - tsum;                 // exclusive within wave
    __shared__ int ws[4];
    if (lane == 63) ws[t >> 6] = x;
    __syncthreads();
    int off0 = bsum[blockIdx.x];
    for (int w2 = 0; w2 < (t >> 6); ++w2) off0 += ws[w2];
    int e0 = off0 + wex;
    if (idx < n)     { row[idx]     = e0;        cursor[idx]     = e0; }
    if (idx + 1 < n) { row[idx + 1] = e0 + v.x;  cursor[idx + 1] = e0 + v.x; }
    if (idx + 2 < n) { row[idx + 2] = e0 + s1;   cursor[idx + 2] = e0 + s1; }
    if (idx + 3 < n) { row[idx + 3] = e0 + s2;   cursor[idx + 3] = e0 + s2; }
}

__global__ void fill_kernel(const int* __restrict__ dst, int* __restrict__ cursor,
                            int* __restrict__ eid, int E)
{
    int t = blockIdx.x * blockDim.x + threadIdx.x;
    if (t < E) {
        int pos = atomicAdd(&cursor[dst[t]], 1);
        eid[pos] = t;
    }
}

__global__ void edge_kernel(const float* __restrict__ el, const float* __restrict__ er,
                            const int* __restrict__ src, const int* __restrict__ dst,
                            float* __restrict__ e, int E, int H)
{
    int t = blockIdx.x * blockDim.x + threadIdx.x;
    if (t >= E) return;
    int s = src[t], d = dst[t];
    for (int h = 0; h < H; ++h) {
        float v = el[s * H + h] + er[d * H + h];
        e[t * H + h] = (v > 0.f) ? v : 0.2f * v;
    }
}

// ---------------- per-dst-node softmax + weighted gather (bf16 h) ----------------
// H=2: lanes 0..31 = head 0 (ch 0..127), lanes 32..63 = head 1; each half walks
//      ALL edges (stride 32), reduces within the half.  H=1: full wave, stride 64.
__global__ __launch_bounds__(256) void agg_kernel(
    const unsigned short* __restrict__ h, const float* __restrict__ e,
    const int* __restrict__ row, const int* __restrict__ eidx,
    const int* __restrict__ src, const float* __restrict__ bias,
    float* __restrict__ outf, unsigned short* __restrict__ outb,
    int n_nodes, int H, int do_relu, int zero0)
{
    int wid = blockIdx.x * 4 + (threadIdx.x >> 6);
    if (wid >= n_nodes) return;
    int lane = threadIdx.x & 63;
    int beg = row[wid], end = row[wid + 1];
    int hsel = (H == 2 && lane >= 32) ? 1 : 0;
    int lim    = (H == 2) ? 16 : 32;
    int stride = (H == 2) ? 32 : 64;
    int l0     = (H == 2) ? (lane & 31) : lane;

    float m = -1e30f;
    for (int i = beg + l0; i < end; i += stride)
        m = fmaxf(m, e[eidx[i] * H + hsel]);
    for (int off = lim; off; off >>= 1) m = fmaxf(m, __shfl_xor(m, off));

    float s = 0.f;
    for (int i = beg + l0; i < end; i += stride)
        s += __expf(e[eidx[i] * H + hsel] - m);
    for (int off = lim; off; off >>= 1) s += __shfl_xor(s, off);
    float r = (s > 0.f) ? 1.f / s : 0.f;

    float aA0 = 0.f, aA1 = 0.f, aA2 = 0.f, aA3 = 0.f;
    float aB0 = 0.f, aB1 = 0.f, aB2 = 0.f, aB3 = 0.f;
    float aC0 = 0.f, aC1 = 0.f, aC2 = 0.f, aC3 = 0.f;
    float aD0 = 0.f, aD1 = 0.f, aD2 = 0.f, aD3 = 0.f;
    int i = beg;
    for (; i + 3 < end; i += 4) {
        int ea = eidx[i], eb = eidx[i + 1], ec = eidx[i + 2], ed = eidx[i + 3];
        int sa = src[ea], sb = src[eb], sc = src[ec], sd = src[ed];
        float wa = __expf(e[ea * H + hsel] - m) * r;
        float wb = __expf(e[eb * H + hsel] - m) * r;
        float wc = __expf(e[ec * H + hsel] - m) * r;
        float wd = __expf(e[ed * H + hsel] - m) * r;
        ushort4 ha = *(const ushort4*)(h + (size_t)sa * 256 + lane * 4);
        ushort4 hb = *(const ushort4*)(h + (size_t)sb * 256 + lane * 4);
        ushort4 hc = *(const ushort4*)(h + (size_t)sc * 256 + lane * 4);
        ushort4 hd = *(const ushort4*)(h + (size_t)sd * 256 + lane * 4);
        aA0 = fmaf(wa, bf2f(ha.x), aA0); aB0 = fmaf(wb, bf2f(hb.x), aB0);
        aC0 = fmaf(wc, bf2f(hc.x), aC0); aD0 = fmaf(wd, bf2f(hd.x), aD0);
        aA1 = fmaf(wa, bf2f(ha.y), aA1); aB1 = fmaf(wb, bf2f(hb.y), aB1);
        aC1 = fmaf(wc, bf2f(hc.y), aC1); aD1 = fmaf(wd, bf2f(hd.y), aD1);
        aA2 = fmaf(wa, bf2f(ha.z), aA2); aB2 = fmaf(wb, bf2f(hb.z), aB2);
        aC2 = fmaf(wc, bf2f(hc.z), aC2); aD2 = fmaf(wd, bf2f(hd.z), aD2);
        aA3 = fmaf(wa, bf2f(ha.w), aA3); aB3 = fmaf(wb, bf2f(hb.w), aB3);
        aC3 = fmaf(wc, bf2f(hc.w), aC3); aD3 = fmaf(wd, bf2f(hd.w), aD3);
    }
    for (; i < end; ++i) {
        int ea = eidx[i];
        int sa = src[ea];
        float wa = __expf(e[ea * H + hsel] - m) * r;
        ushort4 ha = *(const ushort4*)(h + (size_t)sa * 256 + lane * 4);
        aA0 = fmaf(wa, bf2f(ha.x), aA0);
        aA1 = fmaf(wa, bf2f(ha.y), aA1);
        aA2 = fmaf(wa, bf2f(ha.z), aA2);
        aA3 = fmaf(wa, bf2f(ha.w), aA3);
    }

    float4 b4 = *(const float4*)(bias + lane * 4);
    float o0 = (aA0 + aB0) + (aC0 + aD0) + b4.x;
    float o1 = (aA1 + aB1) + (aC1 + aD1) + b4.y;
    float o2 = (aA2 + aB2) + (aC2 + aD2) + b4.z;
    float o3 = (aA3 + aB3) + (aC3 + aD3) + b4.w;
    if (do_relu) {
        o0 = fmaxf(o0, 0.f); o1 = fmaxf(o1, 0.f);
        o2 = fmaxf(o2, 0.f); o3 = fmaxf(o3, 0.f);
    }
    if (zero0 && wid == 0) { o0 = o1 = o2 = o3 = 0.f; }
    size_t base = (size_t)wid * 256 + lane * 4;
    if (outb) {
        ushort4 o; o.x = f2bf(o0); o.y = f2bf(o1); o.z = f2bf(o2); o.w = f2bf(o3);
        *(ushort4*)(outb + base) = o;
    } else {
        *(float4*)(outf + base) = make_float4(o0, o1, o2, o3);
    }
}

extern "C" void kernel_launch(void* const* d_in, const int* in_sizes, int n_in,
                              void* d_out, int out_size, void* d_ws, size_t ws_size,
                              hipStream_t stream)
{
    const float* emb = (const float*)d_in[0];
    const float* W0  = (const float*)d_in[1];
    const float* al0 = (const float*)d_in[2];
    const float* ar0 = (const float*)d_in[3];
    const float* b0  = (const float*)d_in[4];
    const float* W1  = (const float*)d_in[5];
    const float* al1 = (const float*)d_in[6];
    const float* ar1 = (const float*)d_in[7];
    const float* b1  = (const float*)d_in[8];
    const int* src   = (const int*)d_in[9];
    const int* dst   = (const int*)d_in[10];
    const int N = in_sizes[0] / 128;     // 50000
    const int E = in_sizes[9];           // 800000
    float* outp = (float*)d_out;

    char* w = (char*)d_ws;
    auto alloc = [&](size_t bytes) {
        char* p = w;
        w += (bytes + 255) & ~(size_t)255;
        return p;
    };
    unsigned short* hb  = (unsigned short*)alloc((size_t)N * 256 * 2); // h0/h1 bf16
    unsigned short* x1b = (unsigned short*)alloc((size_t)N * 256 * 2); // x1 bf16
    unsigned short* embb = x1b;  // alias: emb bf16 lives here until agg0 writes x1
    float* ebuf = (float*)alloc((size_t)E * 2 * 4);
    int* eid    = (int*)alloc((size_t)E * 4);
    int* rowp   = (int*)alloc((size_t)(N + 1) * 4);
    float* el   = (float*)alloc((size_t)N * 2 * 4);
    float* er   = (float*)alloc((size_t)N * 2 * 4);
    int* cnt    = (int*)el;     // alias: dead before eler writes el
    int* cursor = (int*)er;     // alias: dead before eler writes er
    int* bsum   = (int*)alloc(1024 * 4);
    unsigned short* W0t = (unsigned short*)alloc(256 * 128 * 2);
    unsigned short* W1t = (unsigned short*)alloc(256 * 256 * 2);

    const int nbScan = (N + 1023) / 1024;   // 49

    // converts
    conv_f32_bf16<<<(N * 128 / 4 + 255) / 256, 256, 0, stream>>>(emb, embb, N * 128);
    convW<<<(128 * 256 + 255) / 256, 256, 0, stream>>>(W0, W0t, 128, 256);
    convW<<<(256 * 256 + 255) / 256, 256, 0, stream>>>(W1, W1t, 256, 256);

    // CSR build (dst -> edge list), parallel scan
    hipMemsetAsync(cnt, 0, (size_t)N * 4, stream);
    count_kernel<<<(E + 255) / 256, 256, 0, stream>>>(dst, cnt, E);
    scan_partial<<<nbScan, 256, 0, stream>>>(cnt, bsum, N);
    scan_bsum<<<1, 64, 0, stream>>>(bsum, rowp, nbScan, N, E);
    scan_final<<<nbScan, 256, 0, stream>>>(cnt, bsum, rowp, cursor, N);
    fill_kernel<<<(E + 255) / 256, 256, 0, stream>>>(dst, cursor, eid, E);

    // --- layer 0 (H=2): x1 = relu(agg + b0) -> bf16 x1b ---
    gemm_bf16<<<dim3((N + 127) / 128, 4), 256, 0, stream>>>(embb, W0t, hb, N, 256, 128);
    eler_kernel<<<(N + 3) / 4, 256, 0, stream>>>(hb, al0, ar0, el, er, N, 2);
    edge_kernel<<<(E + 255) / 256, 256, 0, stream>>>(el, er, src, dst, ebuf, E, 2);
    agg_kernel<<<(N + 3) / 4, 256, 0, stream>>>(hb, ebuf, rowp, eid, src, b0,
                                                nullptr, x1b, N, 2, 1, 0);

    // --- layer 1 (H=1): out = agg + b1, row0 zeroed, fp32 out ---
    gemm_bf16<<<dim3((N + 127) / 128, 4), 256, 0, stream>>>(x1b, W1t, hb, N, 256, 256);
    eler_kernel<<<(N + 3) / 4, 256, 0, stream>>>(hb, al1, ar1, el, er, N, 1);
    edge_kernel<<<(E + 255) / 256, 256, 0, stream>>>(el, er, src, dst, ebuf, E, 1);
    agg_kernel<<<(N + 3) / 4, 256, 0, stream>>>(hb, ebuf, rowp, eid, src, b1,
                                                outp, nullptr, N, 1, 0, 1);
}

// Round 6
// 318.745 us; speedup vs baseline: 2.2678x; 1.2010x over previous
//
#include <hip/hip_runtime.h>

// ---------------------------------------------------------------------------
// GAT 2-layer forward, round 6 (= round 5 + fixed H=1 butterfly reduction).
//  - CSR-ordered edge logits (ecsr, planar per head) + src (srcc)
//  - eler fused into GEMM epilogue (atomicAdd partial row-dots)
//  - emb fp32->bf16 conversion folded into gemm0 staging
// ---------------------------------------------------------------------------

typedef __attribute__((ext_vector_type(8))) short short8v;   // 8 bf16
typedef __attribute__((ext_vector_type(4))) float f32x4;

__device__ inline unsigned short f2bf(float x) {
    union { float f; unsigned int u; } v; v.f = x;
    unsigned int r = v.u + 0x7fffu + ((v.u >> 16) & 1u);   // RNE
    return (unsigned short)(r >> 16);
}
__device__ inline float bf2f(unsigned short h) {
    union { unsigned int u; float f; } v; v.u = ((unsigned int)h) << 16;
    return v.f;
}

// W [K][N] fp32 -> Wt [N][K] bf16
__global__ void convW(const float* __restrict__ W, unsigned short* __restrict__ Wt,
                      int K, int N)
{
    int t = blockIdx.x * blockDim.x + threadIdx.x;
    if (t < K * N) {
        int k = t / N, n2 = t - k * N;
        Wt[n2 * K + k] = f2bf(W[t]);
    }
}

// ---------------- fused GEMM + el/er partial dots ----------------
// C[M][N] = A[M][K] @ Bt[N][K]^T ; el/er accumulated via atomics.
// block tile 128x64, BK=64, 256 threads (4 waves), wave computes 32x64.
template<int AFP32, int H>
__global__ __launch_bounds__(256) void gemm_fused(
    const void* __restrict__ Av, const unsigned short* __restrict__ Bt,
    unsigned short* __restrict__ C,
    const float* __restrict__ al, const float* __restrict__ ar,
    float* __restrict__ el, float* __restrict__ er,
    int M, int N, int K)
{
    __shared__ __align__(16) unsigned short As[128 * 64];
    __shared__ __align__(16) unsigned short Bs[64 * 64];
    const int tid = threadIdx.x;
    const int lane = tid & 63, wv = tid >> 6;
    const int rowBase = blockIdx.x * 128;
    const int colBase = blockIdx.y * 64;

    f32x4 acc[2][4];
    #pragma unroll
    for (int i = 0; i < 2; ++i)
        #pragma unroll
        for (int j = 0; j < 4; ++j)
            acc[i][j] = (f32x4){0.f, 0.f, 0.f, 0.f};

    for (int k0 = 0; k0 < K; k0 += 64) {
        // stage A: 128 rows x 8 chunks(8 bf16); dest chunk = cc ^ (row&7)
        #pragma unroll
        for (int c = tid; c < 128 * 8; c += 256) {
            int row = c >> 3, cc = c & 7;
            int gr = rowBase + row; if (gr >= M) gr = M - 1;
            unsigned short* dstp = &As[row * 64 + (cc ^ (row & 7)) * 8];
            if (AFP32) {
                const float* A = (const float*)Av;
                const float* ap = A + (size_t)gr * K + k0 + cc * 8;
                float4 v0 = *(const float4*)ap;
                float4 v1 = *(const float4*)(ap + 4);
                ushort4 o0, o1;
                o0.x = f2bf(v0.x); o0.y = f2bf(v0.y); o0.z = f2bf(v0.z); o0.w = f2bf(v0.w);
                o1.x = f2bf(v1.x); o1.y = f2bf(v1.y); o1.z = f2bf(v1.z); o1.w = f2bf(v1.w);
                *(ushort4*)dstp = o0;
                *(ushort4*)(dstp + 4) = o1;
            } else {
                const unsigned short* A = (const unsigned short*)Av;
                int4 v = *(const int4*)(A + (size_t)gr * K + k0 + cc * 8);
                *(int4*)dstp = v;
            }
        }
        // stage B: 64 rows(N) x 8 chunks
        #pragma unroll
        for (int c = tid; c < 64 * 8; c += 256) {
            int n2 = c >> 3, cc = c & 7;
            int4 v = *(const int4*)(Bt + (size_t)(colBase + n2) * K + k0 + cc * 8);
            *(int4*)&Bs[n2 * 64 + (cc ^ (n2 & 7)) * 8] = v;
        }
        __syncthreads();

        #pragma unroll
        for (int ks = 0; ks < 64; ks += 32) {
            int kchunk = (ks >> 3) + (lane >> 4);   // 0..7
            short8v af[2], bfr[4];
            #pragma unroll
            for (int fm = 0; fm < 2; ++fm) {
                int ml = wv * 32 + fm * 16 + (lane & 15);
                af[fm] = *(const short8v*)&As[ml * 64 + (kchunk ^ (ml & 7)) * 8];
            }
            #pragma unroll
            for (int fi = 0; fi < 4; ++fi) {
                int nl = fi * 16 + (lane & 15);
                bfr[fi] = *(const short8v*)&Bs[nl * 64 + (kchunk ^ (nl & 7)) * 8];
            }
            #pragma unroll
            for (int fm = 0; fm < 2; ++fm)
                #pragma unroll
                for (int fi = 0; fi < 4; ++fi)
                    acc[fm][fi] = __builtin_amdgcn_mfma_f32_16x16x32_bf16(
                        af[fm], bfr[fi], acc[fm][fi], 0, 0, 0);
        }
        __syncthreads();
    }

    // al/ar for this block's 64 cols (per-lane 4 cols)
    float alv[4], arv[4];
    #pragma unroll
    for (int fi = 0; fi < 4; ++fi) {
        int col = colBase + fi * 16 + (lane & 15);
        alv[fi] = al[col];
        arv[fi] = ar[col];
    }
    const int head = (H == 2) ? (colBase >> 7) : 0;

    // epilogue: C-write + el/er partial dot (reduce over 16-lane col group)
    #pragma unroll
    for (int fm = 0; fm < 2; ++fm) {
        #pragma unroll
        for (int r = 0; r < 4; ++r) {
            int row = rowBase + wv * 32 + fm * 16 + (lane >> 4) * 4 + r;
            float pe = acc[fm][0][r] * alv[0] + acc[fm][1][r] * alv[1]
                     + acc[fm][2][r] * alv[2] + acc[fm][3][r] * alv[3];
            float pr2 = acc[fm][0][r] * arv[0] + acc[fm][1][r] * arv[1]
                      + acc[fm][2][r] * arv[2] + acc[fm][3][r] * arv[3];
            #pragma unroll
            for (int off = 8; off; off >>= 1) {
                pe  += __shfl_xor(pe, off);
                pr2 += __shfl_xor(pr2, off);
            }
            if (row < M) {
                #pragma unroll
                for (int fi = 0; fi < 4; ++fi) {
                    int col = colBase + fi * 16 + (lane & 15);
                    C[(size_t)row * N + col] = f2bf(acc[fm][fi][r]);
                }
                if ((lane & 15) == 0) {
                    atomicAdd(&el[row * H + head], pe);
                    atomicAdd(&er[row * H + head], pr2);
                }
            }
        }
    }
}

// ---------------- CSR build ----------------
__global__ void count_kernel(const int* __restrict__ dst, int* __restrict__ cnt, int E)
{
    int t = blockIdx.x * blockDim.x + threadIdx.x;
    if (t < E) atomicAdd(&cnt[dst[t]], 1);
}

__global__ __launch_bounds__(256) void scan_partial(const int* __restrict__ cnt,
                                                    int* __restrict__ bsum, int n)
{
    int t = threadIdx.x;
    int idx = blockIdx.x * 1024 + t * 4;
    int4 v = make_int4(0, 0, 0, 0);
    if (idx + 3 < n) v = *(const int4*)(cnt + idx);
    else if (idx < n) {
        v.x = cnt[idx];
        if (idx + 1 < n) v.y = cnt[idx + 1];
        if (idx + 2 < n) v.z = cnt[idx + 2];
    }
    int s = v.x + v.y + v.z + v.w;
    #pragma unroll
    for (int off = 32; off; off >>= 1) s += __shfl_xor(s, off);
    __shared__ int ws[4];
    if ((t & 63) == 0) ws[t >> 6] = s;
    __syncthreads();
    if (t == 0) bsum[blockIdx.x] = ws[0] + ws[1] + ws[2] + ws[3];
}

__global__ void scan_bsum(int* __restrict__ bsum, int* __restrict__ row,
                          int nb, int n, int E)
{
    int t = threadIdx.x;   // 64 threads
    if (nb <= 64) {
        int v = (t < nb) ? bsum[t] : 0;
        int x = v;
        #pragma unroll
        for (int off = 1; off < 64; off <<= 1) {
            int y = __shfl_up(x, off);
            if (t >= off) x += y;
        }
        if (t < nb) bsum[t] = x - v;
    } else if (t == 0) {
        int run = 0;
        for (int i = 0; i < nb; ++i) { int v = bsum[i]; bsum[i] = run; run += v; }
    }
    if (t == 0) row[n] = E;
}

__global__ __launch_bounds__(256) void scan_final(
    const int* __restrict__ cnt, const int* __restrict__ bsum,
    int* __restrict__ row, int* __restrict__ cursor, int n)
{
    int t = threadIdx.x;
    int lane = t & 63;
    int idx = blockIdx.x * 1024 + t * 4;
    int4 v = make_int4(0, 0, 0, 0);
    if (idx + 3 < n) v = *(const int4*)(cnt + idx);
    else if (idx < n) {
        v.x = cnt[idx];
        if (idx + 1 < n) v.y = cnt[idx + 1];
        if (idx + 2 < n) v.z = cnt[idx + 2];
    }
    int s1 = v.x + v.y, s2 = s1 + v.z, s3 = s2 + v.w;
    int tsum = s3;
    int x = tsum;
    #pragma unroll
    for (int off = 1; off < 64; off <<= 1) {
        int y = __shfl_up(x, off);
        if (lane >= off) x += y;
    }
    int wex = x - tsum;
    __shared__ int ws[4];
    if (lane == 63) ws[t >> 6] = x;
    __syncthreads();
    int off0 = bsum[blockIdx.x];
    for (int w2 = 0; w2 < (t >> 6); ++w2) off0 += ws[w2];
    int e0 = off0 + wex;
    if (idx < n)     { row[idx]     = e0;        cursor[idx]     = e0; }
    if (idx + 1 < n) { row[idx + 1] = e0 + v.x;  cursor[idx + 1] = e0 + v.x; }
    if (idx + 2 < n) { row[idx + 2] = e0 + s1;   cursor[idx + 2] = e0 + s1; }
    if (idx + 3 < n) { row[idx + 3] = e0 + s2;   cursor[idx + 3] = e0 + s2; }
}

__global__ void fill_kernel(const int* __restrict__ dst, int* __restrict__ cursor,
                            int* __restrict__ eid, int E)
{
    int t = blockIdx.x * blockDim.x + threadIdx.x;
    if (t < E) {
        int pos = atomicAdd(&cursor[dst[t]], 1);
        eid[pos] = t;
    }
}

// ---------------- CSR-ordered edge logits + src ----------------
// ecsr planar: head0 at [0..E), head1 at [E..2E)
template<int H>
__global__ void ecsr_kernel(const int* __restrict__ eid, const int* __restrict__ src,
                            const int* __restrict__ dst, const float* __restrict__ el,
                            const float* __restrict__ er, float* __restrict__ ecsr,
                            int* __restrict__ srcc, int E)
{
    int t = blockIdx.x * blockDim.x + threadIdx.x;
    if (t >= E) return;
    int e = eid[t];
    int s = src[e], d = dst[e];
    srcc[t] = s;
    if (H == 2) {
        float2 l2 = *(const float2*)(el + s * 2);
        float2 r2 = *(const float2*)(er + d * 2);
        float v0 = l2.x + r2.x, v1 = l2.y + r2.y;
        ecsr[t]     = (v0 > 0.f) ? v0 : 0.2f * v0;
        ecsr[E + t] = (v1 > 0.f) ? v1 : 0.2f * v1;
    } else {
        float v = el[s] + er[d];
        ecsr[t] = (v > 0.f) ? v : 0.2f * v;
    }
}

// ---------------- per-dst-node softmax + weighted gather (bf16 h) ----------------
// H=2: lanes 0..31 = head 0 (ch 0..127), lanes 32..63 = head 1.
template<int H>
__global__ __launch_bounds__(256) void agg_kernel(
    const unsigned short* __restrict__ h, const float* __restrict__ ecsr,
    const int* __restrict__ srcc, const int* __restrict__ row,
    const float* __restrict__ bias, float* __restrict__ outf,
    unsigned short* __restrict__ outb, int n_nodes, int E,
    int do_relu, int zero0)
{
    int wid = blockIdx.x * 4 + (threadIdx.x >> 6);
    if (wid >= n_nodes) return;
    int lane = threadIdx.x & 63;
    int beg = __builtin_amdgcn_readfirstlane(row[wid]);
    int end = __builtin_amdgcn_readfirstlane(row[wid + 1]);
    const int hsel   = (H == 2) ? (lane >> 5) : 0;
    const int stride = (H == 2) ? 32 : 64;
    const int l0     = (H == 2) ? (lane & 31) : lane;
    const float* plane = ecsr + (size_t)hsel * E;

    // single-pass online max+sum over this node's logits (sequential reads)
    float m = -1e30f, s = 0.f;
    for (int i = beg + l0; i < end; i += stride) {
        float ev = plane[i];
        float mn = fmaxf(m, ev);
        s = s * __expf(m - mn) + __expf(ev - mn);
        m = mn;
    }
    // butterfly reduce: each offset exactly once.
    // H=2: {16,8,4,2,1} within 32-lane halves; H=1: {32,16,8,4,2,1} full wave.
    #pragma unroll
    for (int off = (H == 2) ? 16 : 32; off; off >>= 1) {
        float mo = __shfl_xor(m, off);
        float so = __shfl_xor(s, off);
        float mn = fmaxf(m, mo);
        s = s * __expf(m - mn) + so * __expf(mo - mn);
        m = mn;
    }
    float r = (s > 0.f) ? 1.f / s : 0.f;

    // weighted gather: uniform metadata reads + 512B h-row gathers
    float aA0 = 0.f, aA1 = 0.f, aA2 = 0.f, aA3 = 0.f;
    float aB0 = 0.f, aB1 = 0.f, aB2 = 0.f, aB3 = 0.f;
    float aC0 = 0.f, aC1 = 0.f, aC2 = 0.f, aC3 = 0.f;
    float aD0 = 0.f, aD1 = 0.f, aD2 = 0.f, aD3 = 0.f;
    int i = beg;
    for (; i + 3 < end; i += 4) {
        float wa = __expf(plane[i]     - m) * r;
        float wb = __expf(plane[i + 1] - m) * r;
        float wc = __expf(plane[i + 2] - m) * r;
        float wd = __expf(plane[i + 3] - m) * r;
        int sa = srcc[i], sb = srcc[i + 1], sc2 = srcc[i + 2], sd = srcc[i + 3];
        ushort4 ha = *(const ushort4*)(h + (size_t)sa * 256 + lane * 4);
        ushort4 hb = *(const ushort4*)(h + (size_t)sb * 256 + lane * 4);
        ushort4 hc = *(const ushort4*)(h + (size_t)sc2 * 256 + lane * 4);
        ushort4 hd = *(const ushort4*)(h + (size_t)sd * 256 + lane * 4);
        aA0 = fmaf(wa, bf2f(ha.x), aA0); aB0 = fmaf(wb, bf2f(hb.x), aB0);
        aC0 = fmaf(wc, bf2f(hc.x), aC0); aD0 = fmaf(wd, bf2f(hd.x), aD0);
        aA1 = fmaf(wa, bf2f(ha.y), aA1); aB1 = fmaf(wb, bf2f(hb.y), aB1);
        aC1 = fmaf(wc, bf2f(hc.y), aC1); aD1 = fmaf(wd, bf2f(hd.y), aD1);
        aA2 = fmaf(wa, bf2f(ha.z), aA2); aB2 = fmaf(wb, bf2f(hb.z), aB2);
        aC2 = fmaf(wc, bf2f(hc.z), aC2); aD2 = fmaf(wd, bf2f(hd.z), aD2);
        aA3 = fmaf(wa, bf2f(ha.w), aA3); aB3 = fmaf(wb, bf2f(hb.w), aB3);
        aC3 = fmaf(wc, bf2f(hc.w), aC3); aD3 = fmaf(wd, bf2f(hd.w), aD3);
    }
    for (; i < end; ++i) {
        float wa = __expf(plane[i] - m) * r;
        int sa = srcc[i];
        ushort4 ha = *(const ushort4*)(h + (size_t)sa * 256 + lane * 4);
        aA0 = fmaf(wa, bf2f(ha.x), aA0);
        aA1 = fmaf(wa, bf2f(ha.y), aA1);
        aA2 = fmaf(wa, bf2f(ha.z), aA2);
        aA3 = fmaf(wa, bf2f(ha.w), aA3);
    }

    float4 b4 = *(const float4*)(bias + lane * 4);
    float o0 = (aA0 + aB0) + (aC0 + aD0) + b4.x;
    float o1 = (aA1 + aB1) + (aC1 + aD1) + b4.y;
    float o2 = (aA2 + aB2) + (aC2 + aD2) + b4.z;
    float o3 = (aA3 + aB3) + (aC3 + aD3) + b4.w;
    if (do_relu) {
        o0 = fmaxf(o0, 0.f); o1 = fmaxf(o1, 0.f);
        o2 = fmaxf(o2, 0.f); o3 = fmaxf(o3, 0.f);
    }
    if (zero0 && wid == 0) { o0 = o1 = o2 = o3 = 0.f; }
    size_t base = (size_t)wid * 256 + lane * 4;
    if (outb) {
        ushort4 o; o.x = f2bf(o0); o.y = f2bf(o1); o.z = f2bf(o2); o.w = f2bf(o3);
        *(ushort4*)(outb + base) = o;
    } else {
        *(float4*)(outf + base) = make_float4(o0, o1, o2, o3);
    }
}

extern "C" void kernel_launch(void* const* d_in, const int* in_sizes, int n_in,
                              void* d_out, int out_size, void* d_ws, size_t ws_size,
                              hipStream_t stream)
{
    const float* emb = (const float*)d_in[0];
    const float* W0  = (const float*)d_in[1];
    const float* al0 = (const float*)d_in[2];
    const float* ar0 = (const float*)d_in[3];
    const float* b0  = (const float*)d_in[4];
    const float* W1  = (const float*)d_in[5];
    const float* al1 = (const float*)d_in[6];
    const float* ar1 = (const float*)d_in[7];
    const float* b1  = (const float*)d_in[8];
    const int* src   = (const int*)d_in[9];
    const int* dst   = (const int*)d_in[10];
    const int N = in_sizes[0] / 128;     // 50000
    const int E = in_sizes[9];           // 800000
    float* outp = (float*)d_out;

    char* w = (char*)d_ws;
    auto alloc = [&](size_t bytes) {
        char* p = w;
        w += (bytes + 255) & ~(size_t)255;
        return p;
    };
    unsigned short* hb  = (unsigned short*)alloc((size_t)N * 256 * 2); // h bf16
    unsigned short* x1b = (unsigned short*)alloc((size_t)N * 256 * 2); // x1 bf16
    float* ecsr = (float*)alloc((size_t)E * 2 * 4);   // planar logits
    int* eid    = (int*)alloc((size_t)E * 4);
    int* srcc   = (int*)alloc((size_t)E * 4);
    int* rowp   = (int*)alloc((size_t)(N + 1) * 4);
    float* el   = (float*)alloc((size_t)N * 2 * 4);
    float* er   = (float*)alloc((size_t)N * 2 * 4);
    int* cnt    = (int*)alloc((size_t)N * 4);
    int* cursor = (int*)alloc((size_t)N * 4);
    int* bsum   = (int*)alloc(1024 * 4);
    unsigned short* W0t = (unsigned short*)alloc(256 * 128 * 2);
    unsigned short* W1t = (unsigned short*)alloc(256 * 256 * 2);

    const int nbScan = (N + 1023) / 1024;   // 49

    // weight converts
    convW<<<(128 * 256 + 255) / 256, 256, 0, stream>>>(W0, W0t, 128, 256);
    convW<<<(256 * 256 + 255) / 256, 256, 0, stream>>>(W1, W1t, 256, 256);

    // CSR build (dst -> edge list)
    hipMemsetAsync(cnt, 0, (size_t)N * 4, stream);
    count_kernel<<<(E + 255) / 256, 256, 0, stream>>>(dst, cnt, E);
    scan_partial<<<nbScan, 256, 0, stream>>>(cnt, bsum, N);
    scan_bsum<<<1, 64, 0, stream>>>(bsum, rowp, nbScan, N, E);
    scan_final<<<nbScan, 256, 0, stream>>>(cnt, bsum, rowp, cursor, N);
    fill_kernel<<<(E + 255) / 256, 256, 0, stream>>>(dst, cursor, eid, E);

    // --- layer 0 (H=2): x1 = relu(agg + b0) -> bf16 x1b ---
    hipMemsetAsync(el, 0, (size_t)N * 2 * 4, stream);
    hipMemsetAsync(er, 0, (size_t)N * 2 * 4, stream);
    gemm_fused<1, 2><<<dim3((N + 127) / 128, 4), 256, 0, stream>>>(
        emb, W0t, hb, al0, ar0, el, er, N, 256, 128);
    ecsr_kernel<2><<<(E + 255) / 256, 256, 0, stream>>>(
        eid, src, dst, el, er, ecsr, srcc, E);
    agg_kernel<2><<<(N + 3) / 4, 256, 0, stream>>>(
        hb, ecsr, srcc, rowp, b0, nullptr, x1b, N, E, 1, 0);

    // --- layer 1 (H=1): out = agg + b1, row0 zeroed, fp32 out ---
    hipMemsetAsync(el, 0, (size_t)N * 4, stream);
    hipMemsetAsync(er, 0, (size_t)N * 4, stream);
    gemm_fused<0, 1><<<dim3((N + 127) / 128, 4), 256, 0, stream>>>(
        x1b, W1t, hb, al1, ar1, el, er, N, 256, 256);
    ecsr_kernel<1><<<(E + 255) / 256, 256, 0, stream>>>(
        eid, src, dst, el, er, ecsr, srcc, E);
    agg_kernel<1><<<(N + 3) / 4, 256, 0, stream>>>(
        hb, ecsr, srcc, rowp, b1, outp, nullptr, N, E, 0, 1);
}

// Round 7
// 315.448 us; speedup vs baseline: 2.2915x; 1.0105x over previous
//
#include <hip/hip_runtime.h>

// ---------------------------------------------------------------------------
// GAT 2-layer forward, round 7.
//  - agg: exp2-prescaled logits (native v_exp), 1/s folded out, unroll 8
//  - eid eliminated: fill writes srcc (CSR-ordered src) directly
//  - ecsr node-parallel: er uniform, srcc coalesced, only el[src] random
// ---------------------------------------------------------------------------

typedef __attribute__((ext_vector_type(8))) short short8v;   // 8 bf16
typedef __attribute__((ext_vector_type(4))) float f32x4;

#define LOG2E 1.4426950408889634f

__device__ inline unsigned short f2bf(float x) {
    union { float f; unsigned int u; } v; v.f = x;
    unsigned int r = v.u + 0x7fffu + ((v.u >> 16) & 1u);   // RNE
    return (unsigned short)(r >> 16);
}
__device__ inline float bf2f(unsigned short h) {
    union { unsigned int u; float f; } v; v.u = ((unsigned int)h) << 16;
    return v.f;
}

// W [K][N] fp32 -> Wt [N][K] bf16
__global__ void convW(const float* __restrict__ W, unsigned short* __restrict__ Wt,
                      int K, int N)
{
    int t = blockIdx.x * blockDim.x + threadIdx.x;
    if (t < K * N) {
        int k = t / N, n2 = t - k * N;
        Wt[n2 * K + k] = f2bf(W[t]);
    }
}

// ---------------- fused GEMM + el/er partial dots ----------------
template<int AFP32, int H>
__global__ __launch_bounds__(256) void gemm_fused(
    const void* __restrict__ Av, const unsigned short* __restrict__ Bt,
    unsigned short* __restrict__ C,
    const float* __restrict__ al, const float* __restrict__ ar,
    float* __restrict__ el, float* __restrict__ er,
    int M, int N, int K)
{
    __shared__ __align__(16) unsigned short As[128 * 64];
    __shared__ __align__(16) unsigned short Bs[64 * 64];
    const int tid = threadIdx.x;
    const int lane = tid & 63, wv = tid >> 6;
    const int rowBase = blockIdx.x * 128;
    const int colBase = blockIdx.y * 64;

    f32x4 acc[2][4];
    #pragma unroll
    for (int i = 0; i < 2; ++i)
        #pragma unroll
        for (int j = 0; j < 4; ++j)
            acc[i][j] = (f32x4){0.f, 0.f, 0.f, 0.f};

    for (int k0 = 0; k0 < K; k0 += 64) {
        #pragma unroll
        for (int c = tid; c < 128 * 8; c += 256) {
            int row = c >> 3, cc = c & 7;
            int gr = rowBase + row; if (gr >= M) gr = M - 1;
            unsigned short* dstp = &As[row * 64 + (cc ^ (row & 7)) * 8];
            if (AFP32) {
                const float* A = (const float*)Av;
                const float* ap = A + (size_t)gr * K + k0 + cc * 8;
                float4 v0 = *(const float4*)ap;
                float4 v1 = *(const float4*)(ap + 4);
                ushort4 o0, o1;
                o0.x = f2bf(v0.x); o0.y = f2bf(v0.y); o0.z = f2bf(v0.z); o0.w = f2bf(v0.w);
                o1.x = f2bf(v1.x); o1.y = f2bf(v1.y); o1.z = f2bf(v1.z); o1.w = f2bf(v1.w);
                *(ushort4*)dstp = o0;
                *(ushort4*)(dstp + 4) = o1;
            } else {
                const unsigned short* A = (const unsigned short*)Av;
                int4 v = *(const int4*)(A + (size_t)gr * K + k0 + cc * 8);
                *(int4*)dstp = v;
            }
        }
        #pragma unroll
        for (int c = tid; c < 64 * 8; c += 256) {
            int n2 = c >> 3, cc = c & 7;
            int4 v = *(const int4*)(Bt + (size_t)(colBase + n2) * K + k0 + cc * 8);
            *(int4*)&Bs[n2 * 64 + (cc ^ (n2 & 7)) * 8] = v;
        }
        __syncthreads();

        #pragma unroll
        for (int ks = 0; ks < 64; ks += 32) {
            int kchunk = (ks >> 3) + (lane >> 4);   // 0..7
            short8v af[2], bfr[4];
            #pragma unroll
            for (int fm = 0; fm < 2; ++fm) {
                int ml = wv * 32 + fm * 16 + (lane & 15);
                af[fm] = *(const short8v*)&As[ml * 64 + (kchunk ^ (ml & 7)) * 8];
            }
            #pragma unroll
            for (int fi = 0; fi < 4; ++fi) {
                int nl = fi * 16 + (lane & 15);
                bfr[fi] = *(const short8v*)&Bs[nl * 64 + (kchunk ^ (nl & 7)) * 8];
            }
            #pragma unroll
            for (int fm = 0; fm < 2; ++fm)
                #pragma unroll
                for (int fi = 0; fi < 4; ++fi)
                    acc[fm][fi] = __builtin_amdgcn_mfma_f32_16x16x32_bf16(
                        af[fm], bfr[fi], acc[fm][fi], 0, 0, 0);
        }
        __syncthreads();
    }

    float alv[4], arv[4];
    #pragma unroll
    for (int fi = 0; fi < 4; ++fi) {
        int col = colBase + fi * 16 + (lane & 15);
        alv[fi] = al[col];
        arv[fi] = ar[col];
    }
    const int head = (H == 2) ? (colBase >> 7) : 0;

    #pragma unroll
    for (int fm = 0; fm < 2; ++fm) {
        #pragma unroll
        for (int r = 0; r < 4; ++r) {
            int row = rowBase + wv * 32 + fm * 16 + (lane >> 4) * 4 + r;
            float pe = acc[fm][0][r] * alv[0] + acc[fm][1][r] * alv[1]
                     + acc[fm][2][r] * alv[2] + acc[fm][3][r] * alv[3];
            float pr2 = acc[fm][0][r] * arv[0] + acc[fm][1][r] * arv[1]
                      + acc[fm][2][r] * arv[2] + acc[fm][3][r] * arv[3];
            #pragma unroll
            for (int off = 8; off; off >>= 1) {
                pe  += __shfl_xor(pe, off);
                pr2 += __shfl_xor(pr2, off);
            }
            if (row < M) {
                #pragma unroll
                for (int fi = 0; fi < 4; ++fi) {
                    int col = colBase + fi * 16 + (lane & 15);
                    C[(size_t)row * N + col] = f2bf(acc[fm][fi][r]);
                }
                if ((lane & 15) == 0) {
                    atomicAdd(&el[row * H + head], pe);
                    atomicAdd(&er[row * H + head], pr2);
                }
            }
        }
    }
}

// ---------------- CSR build ----------------
__global__ void count_kernel(const int* __restrict__ dst, int* __restrict__ cnt, int E)
{
    int t = blockIdx.x * blockDim.x + threadIdx.x;
    if (t < E) atomicAdd(&cnt[dst[t]], 1);
}

__global__ __launch_bounds__(256) void scan_partial(const int* __restrict__ cnt,
                                                    int* __restrict__ bsum, int n)
{
    int t = threadIdx.x;
    int idx = blockIdx.x * 1024 + t * 4;
    int4 v = make_int4(0, 0, 0, 0);
    if (idx + 3 < n) v = *(const int4*)(cnt + idx);
    else if (idx < n) {
        v.x = cnt[idx];
        if (idx + 1 < n) v.y = cnt[idx + 1];
        if (idx + 2 < n) v.z = cnt[idx + 2];
    }
    int s = v.x + v.y + v.z + v.w;
    #pragma unroll
    for (int off = 32; off; off >>= 1) s += __shfl_xor(s, off);
    __shared__ int ws[4];
    if ((t & 63) == 0) ws[t >> 6] = s;
    __syncthreads();
    if (t == 0) bsum[blockIdx.x] = ws[0] + ws[1] + ws[2] + ws[3];
}

__global__ void scan_bsum(int* __restrict__ bsum, int* __restrict__ row,
                          int nb, int n, int E)
{
    int t = threadIdx.x;   // 64 threads
    if (nb <= 64) {
        int v = (t < nb) ? bsum[t] : 0;
        int x = v;
        #pragma unroll
        for (int off = 1; off < 64; off <<= 1) {
            int y = __shfl_up(x, off);
            if (t >= off) x += y;
        }
        if (t < nb) bsum[t] = x - v;
    } else if (t == 0) {
        int run = 0;
        for (int i = 0; i < nb; ++i) { int v = bsum[i]; bsum[i] = run; run += v; }
    }
    if (t == 0) row[n] = E;
}

__global__ __launch_bounds__(256) void scan_final(
    const int* __restrict__ cnt, const int* __restrict__ bsum,
    int* __restrict__ row, int* __restrict__ cursor, int n)
{
    int t = threadIdx.x;
    int lane = t & 63;
    int idx = blockIdx.x * 1024 + t * 4;
    int4 v = make_int4(0, 0, 0, 0);
    if (idx + 3 < n) v = *(const int4*)(cnt + idx);
    else if (idx < n) {
        v.x = cnt[idx];
        if (idx + 1 < n) v.y = cnt[idx + 1];
        if (idx + 2 < n) v.z = cnt[idx + 2];
    }
    int s1 = v.x + v.y, s2 = s1 + v.z, s3 = s2 + v.w;
    int tsum = s3;
    int x = tsum;
    #pragma unroll
    for (int off = 1; off < 64; off <<= 1) {
        int y = __shfl_up(x, off);
        if (lane >= off) x += y;
    }
    int wex = x - tsum;
    __shared__ int ws[4];
    if (lane == 63) ws[t >> 6] = x;
    __syncthreads();
    int off0 = bsum[blockIdx.x];
    for (int w2 = 0; w2 < (t >> 6); ++w2) off0 += ws[w2];
    int e0 = off0 + wex;
    if (idx < n)     { row[idx]     = e0;        cursor[idx]     = e0; }
    if (idx + 1 < n) { row[idx + 1] = e0 + v.x;  cursor[idx + 1] = e0 + v.x; }
    if (idx + 2 < n) { row[idx + 2] = e0 + s1;   cursor[idx + 2] = e0 + s1; }
    if (idx + 3 < n) { row[idx + 3] = e0 + s2;   cursor[idx + 3] = e0 + s2; }
}

// fill: CSR-ordered src directly (no eid indirection)
__global__ void fill_kernel(const int* __restrict__ src, const int* __restrict__ dst,
                            int* __restrict__ cursor, int* __restrict__ srcc, int E)
{
    int t = blockIdx.x * blockDim.x + threadIdx.x;
    if (t < E) {
        int pos = atomicAdd(&cursor[dst[t]], 1);
        srcc[pos] = src[t];
    }
}

// ---------------- node-parallel CSR-ordered logits (prescaled by log2 e) ----
// ecsr planar: head0 at [0..E), head1 at [E..2E)
template<int H>
__global__ __launch_bounds__(256) void ecsr_node(
    const int* __restrict__ srcc, const int* __restrict__ rowp,
    const float* __restrict__ el, const float* __restrict__ er,
    float* __restrict__ ecsr, int n_nodes, int E)
{
    int wid = blockIdx.x * 4 + (threadIdx.x >> 6);
    if (wid >= n_nodes) return;
    int lane = threadIdx.x & 63;
    int beg = rowp[wid], end = rowp[wid + 1];
    if (H == 2) {
        float2 r2 = *(const float2*)(er + wid * 2);
        for (int i = beg + lane; i < end; i += 64) {
            int s = srcc[i];
            float2 l2 = *(const float2*)(el + s * 2);
            float v0 = l2.x + r2.x, v1 = l2.y + r2.y;
            ecsr[i]     = ((v0 > 0.f) ? v0 : 0.2f * v0) * LOG2E;
            ecsr[E + i] = ((v1 > 0.f) ? v1 : 0.2f * v1) * LOG2E;
        }
    } else {
        float rr = er[wid];
        for (int i = beg + lane; i < end; i += 64) {
            float v = el[srcc[i]] + rr;
            ecsr[i] = ((v > 0.f) ? v : 0.2f * v) * LOG2E;
        }
    }
}

// ---------------- per-dst-node softmax + weighted gather (bf16 h) ----------------
template<int H>
__global__ __launch_bounds__(256) void agg_kernel(
    const unsigned short* __restrict__ h, const float* __restrict__ ecsr,
    const int* __restrict__ srcc, const int* __restrict__ row,
    const float* __restrict__ bias, float* __restrict__ outf,
    unsigned short* __restrict__ outb, int n_nodes, int E,
    int do_relu, int zero0)
{
    int wid = blockIdx.x * 4 + (threadIdx.x >> 6);
    if (wid >= n_nodes) return;
    int lane = threadIdx.x & 63;
    int beg = __builtin_amdgcn_readfirstlane(row[wid]);
    int end = __builtin_amdgcn_readfirstlane(row[wid + 1]);
    const int hsel   = (H == 2) ? (lane >> 5) : 0;
    const int stride = (H == 2) ? 32 : 64;
    const int l0     = (H == 2) ? (lane & 31) : lane;
    const float* plane = ecsr + (size_t)hsel * E;

    // online max+sum in log2 domain (logits pre-scaled by log2 e)
    float m = -1e30f, s = 0.f;
    for (int i = beg + l0; i < end; i += stride) {
        float ev = plane[i];
        float mn = fmaxf(m, ev);
        s = s * exp2f(m - mn) + exp2f(ev - mn);
        m = mn;
    }
    #pragma unroll
    for (int off = (H == 2) ? 16 : 32; off; off >>= 1) {
        float mo = __shfl_xor(m, off);
        float so = __shfl_xor(s, off);
        float mn = fmaxf(m, mo);
        s = s * exp2f(m - mn) + so * exp2f(mo - mn);
        m = mn;
    }
    float r = (s > 0.f) ? 1.f / s : 0.f;

    // un-normalized weighted gather (x 1/s applied at the end)
    float aA0 = 0.f, aA1 = 0.f, aA2 = 0.f, aA3 = 0.f;
    float aB0 = 0.f, aB1 = 0.f, aB2 = 0.f, aB3 = 0.f;
    float aC0 = 0.f, aC1 = 0.f, aC2 = 0.f, aC3 = 0.f;
    float aD0 = 0.f, aD1 = 0.f, aD2 = 0.f, aD3 = 0.f;
    int i = beg;
    for (; i + 7 < end; i += 8) {
        float wa = exp2f(plane[i]     - m);
        float wb = exp2f(plane[i + 1] - m);
        float wc = exp2f(plane[i + 2] - m);
        float wd = exp2f(plane[i + 3] - m);
        float we = exp2f(plane[i + 4] - m);
        float wf = exp2f(plane[i + 5] - m);
        float wg = exp2f(plane[i + 6] - m);
        float wh = exp2f(plane[i + 7] - m);
        int sa = srcc[i],     sb = srcc[i + 1], sc2 = srcc[i + 2], sd = srcc[i + 3];
        int se = srcc[i + 4], sf = srcc[i + 5], sg  = srcc[i + 6], sh = srcc[i + 7];
        ushort4 ha = *(const ushort4*)(h + (size_t)sa * 256 + lane * 4);
        ushort4 hb = *(const ushort4*)(h + (size_t)sb * 256 + lane * 4);
        ushort4 hc = *(const ushort4*)(h + (size_t)sc2 * 256 + lane * 4);
        ushort4 hd = *(const ushort4*)(h + (size_t)sd * 256 + lane * 4);
        ushort4 he = *(const ushort4*)(h + (size_t)se * 256 + lane * 4);
        ushort4 hf = *(const ushort4*)(h + (size_t)sf * 256 + lane * 4);
        ushort4 hg = *(const ushort4*)(h + (size_t)sg * 256 + lane * 4);
        ushort4 hh = *(const ushort4*)(h + (size_t)sh * 256 + lane * 4);
        aA0 = fmaf(wa, bf2f(ha.x), aA0); aB0 = fmaf(wb, bf2f(hb.x), aB0);
        aC0 = fmaf(wc, bf2f(hc.x), aC0); aD0 = fmaf(wd, bf2f(hd.x), aD0);
        aA1 = fmaf(wa, bf2f(ha.y), aA1); aB1 = fmaf(wb, bf2f(hb.y), aB1);
        aC1 = fmaf(wc, bf2f(hc.y), aC1); aD1 = fmaf(wd, bf2f(hd.y), aD1);
        aA2 = fmaf(wa, bf2f(ha.z), aA2); aB2 = fmaf(wb, bf2f(hb.z), aB2);
        aC2 = fmaf(wc, bf2f(hc.z), aC2); aD2 = fmaf(wd, bf2f(hd.z), aD2);
        aA3 = fmaf(wa, bf2f(ha.w), aA3); aB3 = fmaf(wb, bf2f(hb.w), aB3);
        aC3 = fmaf(wc, bf2f(hc.w), aC3); aD3 = fmaf(wd, bf2f(hd.w), aD3);
        aA0 = fmaf(we, bf2f(he.x), aA0); aB0 = fmaf(wf, bf2f(hf.x), aB0);
        aC0 = fmaf(wg, bf2f(hg.x), aC0); aD0 = fmaf(wh, bf2f(hh.x), aD0);
        aA1 = fmaf(we, bf2f(he.y), aA1); aB1 = fmaf(wf, bf2f(hf.y), aB1);
        aC1 = fmaf(wg, bf2f(hg.y), aC1); aD1 = fmaf(wh, bf2f(hh.y), aD1);
        aA2 = fmaf(we, bf2f(he.z), aA2); aB2 = fmaf(wf, bf2f(hf.z), aB2);
        aC2 = fmaf(wg, bf2f(hg.z), aC2); aD2 = fmaf(wh, bf2f(hh.z), aD2);
        aA3 = fmaf(we, bf2f(he.w), aA3); aB3 = fmaf(wf, bf2f(hf.w), aB3);
        aC3 = fmaf(wg, bf2f(hg.w), aC3); aD3 = fmaf(wh, bf2f(hh.w), aD3);
    }
    for (; i + 3 < end; i += 4) {
        float wa = exp2f(plane[i]     - m);
        float wb = exp2f(plane[i + 1] - m);
        float wc = exp2f(plane[i + 2] - m);
        float wd = exp2f(plane[i + 3] - m);
        int sa = srcc[i], sb = srcc[i + 1], sc2 = srcc[i + 2], sd = srcc[i + 3];
        ushort4 ha = *(const ushort4*)(h + (size_t)sa * 256 + lane * 4);
        ushort4 hb = *(const ushort4*)(h + (size_t)sb * 256 + lane * 4);
        ushort4 hc = *(const ushort4*)(h + (size_t)sc2 * 256 + lane * 4);
        ushort4 hd = *(const ushort4*)(h + (size_t)sd * 256 + lane * 4);
        aA0 = fmaf(wa, bf2f(ha.x), aA0); aB0 = fmaf(wb, bf2f(hb.x), aB0);
        aC0 = fmaf(wc, bf2f(hc.x), aC0); aD0 = fmaf(wd, bf2f(hd.x), aD0);
        aA1 = fmaf(wa, bf2f(ha.y), aA1); aB1 = fmaf(wb, bf2f(hb.y), aB1);
        aC1 = fmaf(wc, bf2f(hc.y), aC1); aD1 = fmaf(wd, bf2f(hd.y), aD1);
        aA2 = fmaf(wa, bf2f(ha.z), aA2); aB2 = fmaf(wb, bf2f(hb.z), aB2);
        aC2 = fmaf(wc, bf2f(hc.z), aC2); aD2 = fmaf(wd, bf2f(hd.z), aD2);
        aA3 = fmaf(wa, bf2f(ha.w), aA3); aB3 = fmaf(wb, bf2f(hb.w), aB3);
        aC3 = fmaf(wc, bf2f(hc.w), aC3); aD3 = fmaf(wd, bf2f(hd.w), aD3);
    }
    for (; i < end; ++i) {
        float wa = exp2f(plane[i] - m);
        int sa = srcc[i];
        ushort4 ha = *(const ushort4*)(h + (size_t)sa * 256 + lane * 4);
        aA0 = fmaf(wa, bf2f(ha.x), aA0);
        aA1 = fmaf(wa, bf2f(ha.y), aA1);
        aA2 = fmaf(wa, bf2f(ha.z), aA2);
        aA3 = fmaf(wa, bf2f(ha.w), aA3);
    }

    float4 b4 = *(const float4*)(bias + lane * 4);
    float o0 = ((aA0 + aB0) + (aC0 + aD0)) * r + b4.x;
    float o1 = ((aA1 + aB1) + (aC1 + aD1)) * r + b4.y;
    float o2 = ((aA2 + aB2) + (aC2 + aD2)) * r + b4.z;
    float o3 = ((aA3 + aB3) + (aC3 + aD3)) * r + b4.w;
    if (do_relu) {
        o0 = fmaxf(o0, 0.f); o1 = fmaxf(o1, 0.f);
        o2 = fmaxf(o2, 0.f); o3 = fmaxf(o3, 0.f);
    }
    if (zero0 && wid == 0) { o0 = o1 = o2 = o3 = 0.f; }
    size_t base = (size_t)wid * 256 + lane * 4;
    if (outb) {
        ushort4 o; o.x = f2bf(o0); o.y = f2bf(o1); o.z = f2bf(o2); o.w = f2bf(o3);
        *(ushort4*)(outb + base) = o;
    } else {
        *(float4*)(outf + base) = make_float4(o0, o1, o2, o3);
    }
}

extern "C" void kernel_launch(void* const* d_in, const int* in_sizes, int n_in,
                              void* d_out, int out_size, void* d_ws, size_t ws_size,
                              hipStream_t stream)
{
    const float* emb = (const float*)d_in[0];
    const float* W0  = (const float*)d_in[1];
    const float* al0 = (const float*)d_in[2];
    const float* ar0 = (const float*)d_in[3];
    const float* b0  = (const float*)d_in[4];
    const float* W1  = (const float*)d_in[5];
    const float* al1 = (const float*)d_in[6];
    const float* ar1 = (const float*)d_in[7];
    const float* b1  = (const float*)d_in[8];
    const int* src   = (const int*)d_in[9];
    const int* dst   = (const int*)d_in[10];
    const int N = in_sizes[0] / 128;     // 50000
    const int E = in_sizes[9];           // 800000
    float* outp = (float*)d_out;

    char* w = (char*)d_ws;
    auto alloc = [&](size_t bytes) {
        char* p = w;
        w += (bytes + 255) & ~(size_t)255;
        return p;
    };
    unsigned short* hb  = (unsigned short*)alloc((size_t)N * 256 * 2); // h bf16
    unsigned short* x1b = (unsigned short*)alloc((size_t)N * 256 * 2); // x1 bf16
    float* ecsr = (float*)alloc((size_t)E * 2 * 4);   // planar prescaled logits
    int* srcc   = (int*)alloc((size_t)E * 4);
    int* rowp   = (int*)alloc((size_t)(N + 1) * 4);
    float* el   = (float*)alloc((size_t)N * 2 * 4);
    float* er   = (float*)alloc((size_t)N * 2 * 4);
    int* cnt    = (int*)alloc((size_t)N * 4);
    int* cursor = (int*)alloc((size_t)N * 4);
    int* bsum   = (int*)alloc(1024 * 4);
    unsigned short* W0t = (unsigned short*)alloc(256 * 128 * 2);
    unsigned short* W1t = (unsigned short*)alloc(256 * 256 * 2);

    const int nbScan = (N + 1023) / 1024;   // 49

    // weight converts
    convW<<<(128 * 256 + 255) / 256, 256, 0, stream>>>(W0, W0t, 128, 256);
    convW<<<(256 * 256 + 255) / 256, 256, 0, stream>>>(W1, W1t, 256, 256);

    // CSR build (dst -> CSR-ordered src)
    hipMemsetAsync(cnt, 0, (size_t)N * 4, stream);
    count_kernel<<<(E + 255) / 256, 256, 0, stream>>>(dst, cnt, E);
    scan_partial<<<nbScan, 256, 0, stream>>>(cnt, bsum, N);
    scan_bsum<<<1, 64, 0, stream>>>(bsum, rowp, nbScan, N, E);
    scan_final<<<nbScan, 256, 0, stream>>>(cnt, bsum, rowp, cursor, N);
    fill_kernel<<<(E + 255) / 256, 256, 0, stream>>>(src, dst, cursor, srcc, E);

    // --- layer 0 (H=2): x1 = relu(agg + b0) -> bf16 x1b ---
    hipMemsetAsync(el, 0, (size_t)N * 2 * 4, stream);
    hipMemsetAsync(er, 0, (size_t)N * 2 * 4, stream);
    gemm_fused<1, 2><<<dim3((N + 127) / 128, 4), 256, 0, stream>>>(
        emb, W0t, hb, al0, ar0, el, er, N, 256, 128);
    ecsr_node<2><<<(N + 3) / 4, 256, 0, stream>>>(srcc, rowp, el, er, ecsr, N, E);
    agg_kernel<2><<<(N + 3) / 4, 256, 0, stream>>>(
        hb, ecsr, srcc, rowp, b0, nullptr, x1b, N, E, 1, 0);

    // --- layer 1 (H=1): out = agg + b1, row0 zeroed, fp32 out ---
    hipMemsetAsync(el, 0, (size_t)N * 4, stream);
    hipMemsetAsync(er, 0, (size_t)N * 4, stream);
    gemm_fused<0, 1><<<dim3((N + 127) / 128, 4), 256, 0, stream>>>(
        x1b, W1t, hb, al1, ar1, el, er, N, 256, 256);
    ecsr_node<1><<<(N + 3) / 4, 256, 0, stream>>>(srcc, rowp, el, er, ecsr, N, E);
    agg_kernel<1><<<(N + 3) / 4, 256, 0, stream>>>(
        hb, ecsr, srcc, rowp, b1, outp, nullptr, N, E, 0, 1);
}

// Round 8
// 287.968 us; speedup vs baseline: 2.5102x; 1.0954x over previous
//
#include <hip/hip_runtime.h>

// ---------------------------------------------------------------------------
// GAT 2-layer forward, round 8.
//  - agg: stats pass fuses logit computation (el gather + leaky + log2e) and
//    writes the plane buffer; weighted pass (unroll 4, R6-proven) reads it
//    sequentially. ecsr kernels eliminated.
//  - single convW dispatch for both weight matrices
// ---------------------------------------------------------------------------

typedef __attribute__((ext_vector_type(8))) short short8v;   // 8 bf16
typedef __attribute__((ext_vector_type(4))) float f32x4;

#define LOG2E 1.4426950408889634f

__device__ inline unsigned short f2bf(float x) {
    union { float f; unsigned int u; } v; v.f = x;
    unsigned int r = v.u + 0x7fffu + ((v.u >> 16) & 1u);   // RNE
    return (unsigned short)(r >> 16);
}
__device__ inline float bf2f(unsigned short h) {
    union { unsigned int u; float f; } v; v.u = ((unsigned int)h) << 16;
    return v.f;
}

// both W0 [128][256] and W1 [256][256] -> bf16 transposed [N][K]
__global__ void convW_both(const float* __restrict__ W0, unsigned short* __restrict__ W0t,
                           const float* __restrict__ W1, unsigned short* __restrict__ W1t)
{
    int t = blockIdx.x * blockDim.x + threadIdx.x;
    if (t < 128 * 256) {
        int k = t >> 8, n2 = t & 255;
        W0t[n2 * 128 + k] = f2bf(W0[t]);
    }
    int u = t - 128 * 256;
    if (u >= 0 && u < 256 * 256) {
        int k = u >> 8, n2 = u & 255;
        W1t[n2 * 256 + k] = f2bf(W1[u]);
    }
}

// ---------------- fused GEMM + el/er partial dots ----------------
template<int AFP32, int H>
__global__ __launch_bounds__(256) void gemm_fused(
    const void* __restrict__ Av, const unsigned short* __restrict__ Bt,
    unsigned short* __restrict__ C,
    const float* __restrict__ al, const float* __restrict__ ar,
    float* __restrict__ el, float* __restrict__ er,
    int M, int N, int K)
{
    __shared__ __align__(16) unsigned short As[128 * 64];
    __shared__ __align__(16) unsigned short Bs[64 * 64];
    const int tid = threadIdx.x;
    const int lane = tid & 63, wv = tid >> 6;
    const int rowBase = blockIdx.x * 128;
    const int colBase = blockIdx.y * 64;

    f32x4 acc[2][4];
    #pragma unroll
    for (int i = 0; i < 2; ++i)
        #pragma unroll
        for (int j = 0; j < 4; ++j)
            acc[i][j] = (f32x4){0.f, 0.f, 0.f, 0.f};

    for (int k0 = 0; k0 < K; k0 += 64) {
        #pragma unroll
        for (int c = tid; c < 128 * 8; c += 256) {
            int row = c >> 3, cc = c & 7;
            int gr = rowBase + row; if (gr >= M) gr = M - 1;
            unsigned short* dstp = &As[row * 64 + (cc ^ (row & 7)) * 8];
            if (AFP32) {
                const float* A = (const float*)Av;
                const float* ap = A + (size_t)gr * K + k0 + cc * 8;
                float4 v0 = *(const float4*)ap;
                float4 v1 = *(const float4*)(ap + 4);
                ushort4 o0, o1;
                o0.x = f2bf(v0.x); o0.y = f2bf(v0.y); o0.z = f2bf(v0.z); o0.w = f2bf(v0.w);
                o1.x = f2bf(v1.x); o1.y = f2bf(v1.y); o1.z = f2bf(v1.z); o1.w = f2bf(v1.w);
                *(ushort4*)dstp = o0;
                *(ushort4*)(dstp + 4) = o1;
            } else {
                const unsigned short* A = (const unsigned short*)Av;
                int4 v = *(const int4*)(A + (size_t)gr * K + k0 + cc * 8);
                *(int4*)dstp = v;
            }
        }
        #pragma unroll
        for (int c = tid; c < 64 * 8; c += 256) {
            int n2 = c >> 3, cc = c & 7;
            int4 v = *(const int4*)(Bt + (size_t)(colBase + n2) * K + k0 + cc * 8);
            *(int4*)&Bs[n2 * 64 + (cc ^ (n2 & 7)) * 8] = v;
        }
        __syncthreads();

        #pragma unroll
        for (int ks = 0; ks < 64; ks += 32) {
            int kchunk = (ks >> 3) + (lane >> 4);   // 0..7
            short8v af[2], bfr[4];
            #pragma unroll
            for (int fm = 0; fm < 2; ++fm) {
                int ml = wv * 32 + fm * 16 + (lane & 15);
                af[fm] = *(const short8v*)&As[ml * 64 + (kchunk ^ (ml & 7)) * 8];
            }
            #pragma unroll
            for (int fi = 0; fi < 4; ++fi) {
                int nl = fi * 16 + (lane & 15);
                bfr[fi] = *(const short8v*)&Bs[nl * 64 + (kchunk ^ (nl & 7)) * 8];
            }
            #pragma unroll
            for (int fm = 0; fm < 2; ++fm)
                #pragma unroll
                for (int fi = 0; fi < 4; ++fi)
                    acc[fm][fi] = __builtin_amdgcn_mfma_f32_16x16x32_bf16(
                        af[fm], bfr[fi], acc[fm][fi], 0, 0, 0);
        }
        __syncthreads();
    }

    float alv[4], arv[4];
    #pragma unroll
    for (int fi = 0; fi < 4; ++fi) {
        int col = colBase + fi * 16 + (lane & 15);
        alv[fi] = al[col];
        arv[fi] = ar[col];
    }
    const int head = (H == 2) ? (colBase >> 7) : 0;

    #pragma unroll
    for (int fm = 0; fm < 2; ++fm) {
        #pragma unroll
        for (int r = 0; r < 4; ++r) {
            int row = rowBase + wv * 32 + fm * 16 + (lane >> 4) * 4 + r;
            float pe = acc[fm][0][r] * alv[0] + acc[fm][1][r] * alv[1]
                     + acc[fm][2][r] * alv[2] + acc[fm][3][r] * alv[3];
            float pr2 = acc[fm][0][r] * arv[0] + acc[fm][1][r] * arv[1]
                      + acc[fm][2][r] * arv[2] + acc[fm][3][r] * arv[3];
            #pragma unroll
            for (int off = 8; off; off >>= 1) {
                pe  += __shfl_xor(pe, off);
                pr2 += __shfl_xor(pr2, off);
            }
            if (row < M) {
                #pragma unroll
                for (int fi = 0; fi < 4; ++fi) {
                    int col = colBase + fi * 16 + (lane & 15);
                    C[(size_t)row * N + col] = f2bf(acc[fm][fi][r]);
                }
                if ((lane & 15) == 0) {
                    atomicAdd(&el[row * H + head], pe);
                    atomicAdd(&er[row * H + head], pr2);
                }
            }
        }
    }
}

// ---------------- CSR build ----------------
__global__ void count_kernel(const int* __restrict__ dst, int* __restrict__ cnt, int E)
{
    int t = blockIdx.x * blockDim.x + threadIdx.x;
    if (t < E) atomicAdd(&cnt[dst[t]], 1);
}

__global__ __launch_bounds__(256) void scan_partial(const int* __restrict__ cnt,
                                                    int* __restrict__ bsum, int n)
{
    int t = threadIdx.x;
    int idx = blockIdx.x * 1024 + t * 4;
    int4 v = make_int4(0, 0, 0, 0);
    if (idx + 3 < n) v = *(const int4*)(cnt + idx);
    else if (idx < n) {
        v.x = cnt[idx];
        if (idx + 1 < n) v.y = cnt[idx + 1];
        if (idx + 2 < n) v.z = cnt[idx + 2];
    }
    int s = v.x + v.y + v.z + v.w;
    #pragma unroll
    for (int off = 32; off; off >>= 1) s += __shfl_xor(s, off);
    __shared__ int ws[4];
    if ((t & 63) == 0) ws[t >> 6] = s;
    __syncthreads();
    if (t == 0) bsum[blockIdx.x] = ws[0] + ws[1] + ws[2] + ws[3];
}

__global__ void scan_bsum(int* __restrict__ bsum, int* __restrict__ row,
                          int nb, int n, int E)
{
    int t = threadIdx.x;   // 64 threads
    if (nb <= 64) {
        int v = (t < nb) ? bsum[t] : 0;
        int x = v;
        #pragma unroll
        for (int off = 1; off < 64; off <<= 1) {
            int y = __shfl_up(x, off);
            if (t >= off) x += y;
        }
        if (t < nb) bsum[t] = x - v;
    } else if (t == 0) {
        int run = 0;
        for (int i = 0; i < nb; ++i) { int v = bsum[i]; bsum[i] = run; run += v; }
    }
    if (t == 0) row[n] = E;
}

__global__ __launch_bounds__(256) void scan_final(
    const int* __restrict__ cnt, const int* __restrict__ bsum,
    int* __restrict__ row, int* __restrict__ cursor, int n)
{
    int t = threadIdx.x;
    int lane = t & 63;
    int idx = blockIdx.x * 1024 + t * 4;
    int4 v = make_int4(0, 0, 0, 0);
    if (idx + 3 < n) v = *(const int4*)(cnt + idx);
    else if (idx < n) {
        v.x = cnt[idx];
        if (idx + 1 < n) v.y = cnt[idx + 1];
        if (idx + 2 < n) v.z = cnt[idx + 2];
    }
    int s1 = v.x + v.y, s2 = s1 + v.z, s3 = s2 + v.w;
    int tsum = s3;
    int x = tsum;
    #pragma unroll
    for (int off = 1; off < 64; off <<= 1) {
        int y = __shfl_up(x, off);
        if (lane >= off) x += y;
    }
    int wex = x - tsum;
    __shared__ int ws[4];
    if (lane == 63) ws[t >> 6] = x;
    __syncthreads();
    int off0 = bsum[blockIdx.x];
    for (int w2 = 0; w2 < (t >> 6); ++w2) off0 += ws[w2];
    int e0 = off0 + wex;
    if (idx < n)     { row[idx]     = e0;        cursor[idx]     = e0; }
    if (idx + 1 < n) { row[idx + 1] = e0 + v.x;  cursor[idx + 1] = e0 + v.x; }
    if (idx + 2 < n) { row[idx + 2] = e0 + s1;   cursor[idx + 2] = e0 + s1; }
    if (idx + 3 < n) { row[idx + 3] = e0 + s2;   cursor[idx + 3] = e0 + s2; }
}

// fill: CSR-ordered src directly
__global__ void fill_kernel(const int* __restrict__ src, const int* __restrict__ dst,
                            int* __restrict__ cursor, int* __restrict__ srcc, int E)
{
    int t = blockIdx.x * blockDim.x + threadIdx.x;
    if (t < E) {
        int pos = atomicAdd(&cursor[dst[t]], 1);
        srcc[pos] = src[t];
    }
}

// ---------------- per-dst-node softmax + weighted gather (bf16 h) ----------------
// Stats pass gathers el[src], computes leaky*log2e logit, WRITES plane buffer;
// weighted pass (unroll 4) re-reads plane sequentially (L2-hot).
// H=2: lanes 0..31 = head 0 (ch 0..127), lanes 32..63 = head 1.
template<int H>
__global__ __launch_bounds__(256) void agg_kernel(
    const unsigned short* __restrict__ h, const float* __restrict__ el,
    const float* __restrict__ er, float* __restrict__ ecsr,
    const int* __restrict__ srcc, const int* __restrict__ row,
    const float* __restrict__ bias, float* __restrict__ outf,
    unsigned short* __restrict__ outb, int n_nodes, int E,
    int do_relu, int zero0)
{
    int wid = blockIdx.x * 4 + (threadIdx.x >> 6);
    if (wid >= n_nodes) return;
    int lane = threadIdx.x & 63;
    int beg = __builtin_amdgcn_readfirstlane(row[wid]);
    int end = __builtin_amdgcn_readfirstlane(row[wid + 1]);
    const int hsel   = (H == 2) ? (lane >> 5) : 0;
    const int stride = (H == 2) ? 32 : 64;
    const int l0     = (H == 2) ? (lane & 31) : lane;
    float* plane = ecsr + (size_t)hsel * E;
    const float rr = er[wid * H + hsel];

    // stats pass: gather el[src], leaky, prescale by log2e, write plane, online m/s
    float m = -1e30f, s = 0.f;
    for (int i = beg + l0; i < end; i += stride) {
        int sn = srcc[i];
        float v = el[sn * H + hsel] + rr;
        float ev = ((v > 0.f) ? v : 0.2f * v) * LOG2E;
        plane[i] = ev;
        float mn = fmaxf(m, ev);
        s = s * exp2f(m - mn) + exp2f(ev - mn);
        m = mn;
    }
    #pragma unroll
    for (int off = (H == 2) ? 16 : 32; off; off >>= 1) {
        float mo = __shfl_xor(m, off);
        float so = __shfl_xor(s, off);
        float mn = fmaxf(m, mo);
        s = s * exp2f(m - mn) + so * exp2f(mo - mn);
        m = mn;
    }
    float r = (s > 0.f) ? 1.f / s : 0.f;
    __threadfence_block();   // make plane writes visible to all lanes of this wave

    // un-normalized weighted gather (x 1/s at the end), unroll 4 (R6-proven)
    float aA0 = 0.f, aA1 = 0.f, aA2 = 0.f, aA3 = 0.f;
    float aB0 = 0.f, aB1 = 0.f, aB2 = 0.f, aB3 = 0.f;
    float aC0 = 0.f, aC1 = 0.f, aC2 = 0.f, aC3 = 0.f;
    float aD0 = 0.f, aD1 = 0.f, aD2 = 0.f, aD3 = 0.f;
    int i = beg;
    for (; i + 3 < end; i += 4) {
        float wa = exp2f(plane[i]     - m);
        float wb = exp2f(plane[i + 1] - m);
        float wc = exp2f(plane[i + 2] - m);
        float wd = exp2f(plane[i + 3] - m);
        int sa = srcc[i], sb = srcc[i + 1], sc2 = srcc[i + 2], sd = srcc[i + 3];
        ushort4 ha = *(const ushort4*)(h + (size_t)sa * 256 + lane * 4);
        ushort4 hb = *(const ushort4*)(h + (size_t)sb * 256 + lane * 4);
        ushort4 hc = *(const ushort4*)(h + (size_t)sc2 * 256 + lane * 4);
        ushort4 hd = *(const ushort4*)(h + (size_t)sd * 256 + lane * 4);
        aA0 = fmaf(wa, bf2f(ha.x), aA0); aB0 = fmaf(wb, bf2f(hb.x), aB0);
        aC0 = fmaf(wc, bf2f(hc.x), aC0); aD0 = fmaf(wd, bf2f(hd.x), aD0);
        aA1 = fmaf(wa, bf2f(ha.y), aA1); aB1 = fmaf(wb, bf2f(hb.y), aB1);
        aC1 = fmaf(wc, bf2f(hc.y), aC1); aD1 = fmaf(wd, bf2f(hd.y), aD1);
        aA2 = fmaf(wa, bf2f(ha.z), aA2); aB2 = fmaf(wb, bf2f(hb.z), aB2);
        aC2 = fmaf(wc, bf2f(hc.z), aC2); aD2 = fmaf(wd, bf2f(hd.z), aD2);
        aA3 = fmaf(wa, bf2f(ha.w), aA3); aB3 = fmaf(wb, bf2f(hb.w), aB3);
        aC3 = fmaf(wc, bf2f(hc.w), aC3); aD3 = fmaf(wd, bf2f(hd.w), aD3);
    }
    for (; i < end; ++i) {
        float wa = exp2f(plane[i] - m);
        int sa = srcc[i];
        ushort4 ha = *(const ushort4*)(h + (size_t)sa * 256 + lane * 4);
        aA0 = fmaf(wa, bf2f(ha.x), aA0);
        aA1 = fmaf(wa, bf2f(ha.y), aA1);
        aA2 = fmaf(wa, bf2f(ha.z), aA2);
        aA3 = fmaf(wa, bf2f(ha.w), aA3);
    }

    float4 b4 = *(const float4*)(bias + lane * 4);
    float o0 = ((aA0 + aB0) + (aC0 + aD0)) * r + b4.x;
    float o1 = ((aA1 + aB1) + (aC1 + aD1)) * r + b4.y;
    float o2 = ((aA2 + aB2) + (aC2 + aD2)) * r + b4.z;
    float o3 = ((aA3 + aB3) + (aC3 + aD3)) * r + b4.w;
    if (do_relu) {
        o0 = fmaxf(o0, 0.f); o1 = fmaxf(o1, 0.f);
        o2 = fmaxf(o2, 0.f); o3 = fmaxf(o3, 0.f);
    }
    if (zero0 && wid == 0) { o0 = o1 = o2 = o3 = 0.f; }
    size_t base = (size_t)wid * 256 + lane * 4;
    if (outb) {
        ushort4 o; o.x = f2bf(o0); o.y = f2bf(o1); o.z = f2bf(o2); o.w = f2bf(o3);
        *(ushort4*)(outb + base) = o;
    } else {
        *(float4*)(outf + base) = make_float4(o0, o1, o2, o3);
    }
}

extern "C" void kernel_launch(void* const* d_in, const int* in_sizes, int n_in,
                              void* d_out, int out_size, void* d_ws, size_t ws_size,
                              hipStream_t stream)
{
    const float* emb = (const float*)d_in[0];
    const float* W0  = (const float*)d_in[1];
    const float* al0 = (const float*)d_in[2];
    const float* ar0 = (const float*)d_in[3];
    const float* b0  = (const float*)d_in[4];
    const float* W1  = (const float*)d_in[5];
    const float* al1 = (const float*)d_in[6];
    const float* ar1 = (const float*)d_in[7];
    const float* b1  = (const float*)d_in[8];
    const int* src   = (const int*)d_in[9];
    const int* dst   = (const int*)d_in[10];
    const int N = in_sizes[0] / 128;     // 50000
    const int E = in_sizes[9];           // 800000
    float* outp = (float*)d_out;

    char* w = (char*)d_ws;
    auto alloc = [&](size_t bytes) {
        char* p = w;
        w += (bytes + 255) & ~(size_t)255;
        return p;
    };
    unsigned short* hb  = (unsigned short*)alloc((size_t)N * 256 * 2); // h bf16
    unsigned short* x1b = (unsigned short*)alloc((size_t)N * 256 * 2); // x1 bf16
    float* ecsr = (float*)alloc((size_t)E * 2 * 4);   // planar prescaled logits
    int* srcc   = (int*)alloc((size_t)E * 4);
    int* rowp   = (int*)alloc((size_t)(N + 1) * 4);
    float* el   = (float*)alloc((size_t)N * 2 * 4);
    float* er   = (float*)alloc((size_t)N * 2 * 4);
    int* cnt    = (int*)alloc((size_t)N * 4);
    int* cursor = (int*)alloc((size_t)N * 4);
    int* bsum   = (int*)alloc(1024 * 4);
    unsigned short* W0t = (unsigned short*)alloc(256 * 128 * 2);
    unsigned short* W1t = (unsigned short*)alloc(256 * 256 * 2);

    const int nbScan = (N + 1023) / 1024;   // 49

    // both weight converts in one dispatch
    convW_both<<<(128 * 256 + 256 * 256 + 255) / 256, 256, 0, stream>>>(
        W0, W0t, W1, W1t);

    // CSR build (dst -> CSR-ordered src)
    hipMemsetAsync(cnt, 0, (size_t)N * 4, stream);
    count_kernel<<<(E + 255) / 256, 256, 0, stream>>>(dst, cnt, E);
    scan_partial<<<nbScan, 256, 0, stream>>>(cnt, bsum, N);
    scan_bsum<<<1, 64, 0, stream>>>(bsum, rowp, nbScan, N, E);
    scan_final<<<nbScan, 256, 0, stream>>>(cnt, bsum, rowp, cursor, N);
    fill_kernel<<<(E + 255) / 256, 256, 0, stream>>>(src, dst, cursor, srcc, E);

    // --- layer 0 (H=2): x1 = relu(agg + b0) -> bf16 x1b ---
    hipMemsetAsync(el, 0, (size_t)N * 2 * 4, stream);
    hipMemsetAsync(er, 0, (size_t)N * 2 * 4, stream);
    gemm_fused<1, 2><<<dim3((N + 127) / 128, 4), 256, 0, stream>>>(
        emb, W0t, hb, al0, ar0, el, er, N, 256, 128);
    agg_kernel<2><<<(N + 3) / 4, 256, 0, stream>>>(
        hb, el, er, ecsr, srcc, rowp, b0, nullptr, x1b, N, E, 1, 0);

    // --- layer 1 (H=1): out = agg + b1, row0 zeroed, fp32 out ---
    hipMemsetAsync(el, 0, (size_t)N * 4, stream);
    hipMemsetAsync(er, 0, (size_t)N * 4, stream);
    gemm_fused<0, 1><<<dim3((N + 127) / 128, 4), 256, 0, stream>>>(
        x1b, W1t, hb, al1, ar1, el, er, N, 256, 256);
    agg_kernel<1><<<(N + 3) / 4, 256, 0, stream>>>(
        hb, el, er, ecsr, srcc, rowp, b1, outp, nullptr, N, E, 0, 1);
}